// Round 2
// baseline (270.151 us; speedup 1.0000x reference)
//
#include <hip/hip_runtime.h>
#include <cstdint>
#include <cstddef>

// GATNet on MI355X — round 15.
// Numerics = round 10/11 (passing, absmax 2.0): bf16-hi MFMA approx scores,
// window max-(100+0.04|max|), exact fp32 sparse softmax refinement.
// Round-15 change: attn6 main loop restructured from 4-wave cooperative
// staging (2 __syncthreads per 64-row iter -> compiler drains vmcnt(0) at
// every barrier, killing the prefetch pipeline) to WAVE-PRIVATE double-
// buffered staging: each wave owns 2x4KB LDS buffers, stages its own 16-row
// chunk via 4 global_load_lds, and waits with counted `s_waitcnt vmcnt(4)`
// (never 0) -- no barriers in the main loop at all. Same swizzle, same mask
// logic (bit = it&31, word = it&32). Epilogue + attn6w unchanged (A/B).

typedef short short8 __attribute__((ext_vector_type(8)));
typedef float f32x4  __attribute__((ext_vector_type(4)));
typedef unsigned short u16;
typedef unsigned char  u8;
typedef unsigned int   u32;

#define GLOBAL_AS __attribute__((address_space(1)))
#define LDS_AS    __attribute__((address_space(3)))

__device__ __forceinline__ u16 f2bf(float f) {        // RNE float->bf16 bits
    u32 x = __float_as_uint(f);
    u32 r = (x + 0x7FFFu + ((x >> 16) & 1u)) >> 16;
    return (u16)r;
}

// ---------------------------------------------------------------- K0: graph -> residue-bucketed bitmasks
__global__ __launch_bounds__(256) void pack_adj3(const float* __restrict__ g,
                                                 u32* __restrict__ adjx) {
    int n = blockIdx.x, t = threadIdx.x;
    __shared__ u8 bits[1024];
    float4 v = *(const float4*)&g[(size_t)n * 1024 + t * 4];
    bits[t * 4 + 0] = v.x != 0.0f;
    bits[t * 4 + 1] = v.y != 0.0f;
    bits[t * 4 + 2] = v.z != 0.0f;
    bits[t * 4 + 3] = v.w != 0.0f;
    __syncthreads();
    if (t < 32) {
        int r = t >> 1, h = t & 1;
        u32 wd = 0;
#pragma unroll
        for (int j = 0; j < 32; ++j)
            wd |= (u32)bits[16 * (h * 32 + j) + r] << j;
        adjx[((size_t)n * 16 + r) * 2 + h] = wd;
    }
}

// ---------------------------------------------------------------- K1: h = x @ Wh  (fp32 exact + bf16-hi copy)
__global__ __launch_bounds__(256) void proj1(const float* __restrict__ x,
                                             const float* __restrict__ Whg,
                                             float* __restrict__ hf,
                                             u16* __restrict__ hhi) {
    int bh = blockIdx.x;                 // b*8+hd
    int hd = bh & 7, bb = bh >> 3;
    int n0 = blockIdx.y * 128;
    const float* W  = Whg + (size_t)hd * 64 * 128;
    const float* xb = x + ((size_t)bb * 1024 + n0) * 64;
    __shared__ __attribute__((aligned(16))) float ws[32][132];
    __shared__ __attribute__((aligned(16))) float xsT[32][132];
    int t = threadIdx.x;
    int rg = t >> 4, cg = t & 15;
    int r0 = rg * 8, c0 = cg * 8;
    float acc[8][8] = {};
    for (int kt = 0; kt < 2; ++kt) {
        int kb = kt * 32;
        for (int u = t; u < 1024; u += 256) {
            int k = u >> 5, d4 = (u & 31) << 2;
            *(float4*)&ws[k][d4] = *(const float4*)&W[(size_t)(kb + k) * 128 + d4];
        }
        for (int u = t; u < 1024; u += 256) {
            int r = u >> 3, k4 = (u & 7) << 2;
            float4 xv = *(const float4*)&xb[(size_t)r * 64 + kb + k4];
            xsT[k4 + 0][r] = xv.x; xsT[k4 + 1][r] = xv.y;
            xsT[k4 + 2][r] = xv.z; xsT[k4 + 3][r] = xv.w;
        }
        __syncthreads();
        for (int k = 0; k < 32; ++k) {
            float4 xa = *(float4*)&xsT[k][r0];
            float4 xbv = *(float4*)&xsT[k][r0 + 4];
            float4 wa = *(float4*)&ws[k][c0];
            float4 wb = *(float4*)&ws[k][c0 + 4];
            float xq[8] = {xa.x, xa.y, xa.z, xa.w, xbv.x, xbv.y, xbv.z, xbv.w};
            float wv[8] = {wa.x, wa.y, wa.z, wa.w, wb.x, wb.y, wb.z, wb.w};
#pragma unroll
            for (int i = 0; i < 8; ++i)
#pragma unroll
                for (int j = 0; j < 8; ++j)
                    acc[i][j] = fmaf(xq[i], wv[j], acc[i][j]);
        }
        __syncthreads();
    }
#pragma unroll
    for (int i = 0; i < 8; ++i) {
        int n = n0 + r0 + i;
        size_t base = ((size_t)bh * 1024 + n) * 128 + c0;
        float4 f0 = {acc[i][0], acc[i][1], acc[i][2], acc[i][3]};
        float4 f1 = {acc[i][4], acc[i][5], acc[i][6], acc[i][7]};
        *(float4*)&hf[base]     = f0;
        *(float4*)&hf[base + 4] = f1;
        uint4 up;
        up.x = (u32)f2bf(acc[i][0]) | ((u32)f2bf(acc[i][1]) << 16);
        up.y = (u32)f2bf(acc[i][2]) | ((u32)f2bf(acc[i][3]) << 16);
        up.z = (u32)f2bf(acc[i][4]) | ((u32)f2bf(acc[i][5]) << 16);
        up.w = (u32)f2bf(acc[i][6]) | ((u32)f2bf(acc[i][7]) << 16);
        *(uint4*)&hhi[base] = up;
    }
}

// ---------------------------------------------------------------- K3a: proj2 partials (split-K x8, k-major LDS)
__global__ __launch_bounds__(256) void proj2p(const float* __restrict__ x2,
                                              const float* __restrict__ Wo,
                                              float* __restrict__ ps) {
    int b = blockIdx.x;
    int n0 = blockIdx.y * 128;
    int kz = blockIdx.z;                  // 8 slices x 128 k
    __shared__ __attribute__((aligned(16))) float xsT[32][132];
    __shared__ __attribute__((aligned(16))) float ws[32][68];
    int t = threadIdx.x;
    int nq = t >> 4, jq = t & 15;
    int rA = nq * 8, jA = jq * 4;
    float acc[8][4] = {};
    for (int kt = 0; kt < 4; ++kt) {
        int k0 = kz * 128 + kt * 32;
        for (int u = t; u < 1024; u += 256) {
            int r = u >> 3, k4 = (u & 7) << 2;
            float4 xv = *(const float4*)&x2[((size_t)b * 1024 + n0 + r) * 1024 + k0 + k4];
            xsT[k4 + 0][r] = xv.x; xsT[k4 + 1][r] = xv.y;
            xsT[k4 + 2][r] = xv.z; xsT[k4 + 3][r] = xv.w;
        }
        for (int u = t; u < 512; u += 256) {
            int k = u >> 4, j4 = (u & 15) << 2;
            *(float4*)&ws[k][j4] = *(const float4*)&Wo[(size_t)(k0 + k) * 64 + j4];
        }
        __syncthreads();
        for (int kk = 0; kk < 32; ++kk) {
            float4 xa = *(float4*)&xsT[kk][rA];
            float4 xb = *(float4*)&xsT[kk][rA + 4];
            float4 wv = *(float4*)&ws[kk][jA];
            float xq[8] = {xa.x, xa.y, xa.z, xa.w, xb.x, xb.y, xb.z, xb.w};
            float wq[4] = {wv.x, wv.y, wv.z, wv.w};
#pragma unroll
            for (int i = 0; i < 8; ++i)
#pragma unroll
                for (int j = 0; j < 4; ++j)
                    acc[i][j] = fmaf(xq[i], wq[j], acc[i][j]);
        }
        __syncthreads();
    }
    float* pso = ps + (size_t)kz * 1048576;
#pragma unroll
    for (int i = 0; i < 8; ++i) {
        int n = n0 + rA + i;
        float4 f0 = {acc[i][0], acc[i][1], acc[i][2], acc[i][3]};
        *(float4*)&pso[((size_t)b * 1024 + n) * 64 + jA] = f0;
    }
}

// ---------------------------------------------------------------- K3b: reduce 8 partials -> h2f + h2hi
__global__ __launch_bounds__(256) void reduce2(const float* __restrict__ ps,
                                               float* __restrict__ h2f,
                                               u16* __restrict__ h2hi) {
    size_t e = ((size_t)blockIdx.x * 256 + threadIdx.x) * 4;
    float4 s = {0.f, 0.f, 0.f, 0.f};
#pragma unroll
    for (int i = 0; i < 8; ++i) {
        float4 a = *(const float4*)&ps[e + (size_t)i * 1048576];
        s.x += a.x; s.y += a.y; s.z += a.z; s.w += a.w;
    }
    *(float4*)&h2f[e] = s;
    uint2 up;
    up.x = (u32)f2bf(s.x) | ((u32)f2bf(s.y) << 16);
    up.y = (u32)f2bf(s.z) | ((u32)f2bf(s.w) << 16);
    *(uint2*)&h2hi[e] = up;
}

// ---------------------------------------------------------------- K2: L1 fused masked attention
// Wave-private double-buffered staging, barrier-free main loop with counted
// vmcnt. 32768 B LDS (epilogue aliases the staging region).
template <int DK, int NH, int ORS, int RT>
__global__ __launch_bounds__(256, 4) void attn6(const u16* __restrict__ hhi,
                                                const float* __restrict__ hf,
                                                const u32* __restrict__ adjx,
                                                const float* __restrict__ bias,
                                                float* __restrict__ outp) {
    constexpr int CR   = DK / 8;          // 16 slots/row
    constexpr int NC   = DK / 32;         // 4 k-chunks per MFMA row
    constexpr int RW   = RT / 4;
    constexpr int RS   = RW / 16;
    constexpr int NBH  = NH * 16;
    constexpr int CMAX = 16;
    constexpr int PBUF = 16 * DK;         // u16 per private buffer (4 KB)
    const u32 NEGK = 0xFF800000u;

    int bx = blockIdx.x;
    int bh = bx % NBH, tile = bx / NBH;   // XCD swizzle: bx%8 == bh%8
    int hd = (NH == 1) ? 0 : (bh & (NH - 1));
    int b  = (NH == 1) ? bh : (bh >> 3);
    int n0 = tile * RT;
    const u16*   Hhi = hhi + (size_t)bh * 1024 * DK;
    const float* Hf  = hf  + (size_t)bh * 1024 * DK;
    const float* bs  = bias + (size_t)hd * DK;
    float* ob = outp + (size_t)b * 1024 * ORS + (size_t)hd * DK;

    // LDS = 4 waves x 2 x 4KB private staging; epilogue arrays alias it.
    __shared__ __attribute__((aligned(16))) char smem[32768];
    u16* Ksh = (u16*)smem;
    int   (*candm)[CMAX] = (int(*)[CMAX])smem;               // 8 KB @ 0
    float (*cands)[CMAX] = (float(*)[CMAX])(smem + 8192);    // 8 KB @ 8K
    int*   cnt           = (int*)(smem + 16384);             // 512 B @ 16K
    int*   wl            = (int*)(smem + 16896);             // 8 KB @ 16.5K
    int*   wln           = (int*)(smem + 25088);             // 4 B

    int t = threadIdx.x, lane = t & 63, w = t >> 6;
    int l15 = lane & 15, q4 = lane >> 4;

    u16* KshW = Ksh + w * 2 * PBUF;       // this wave's 8 KB region

    uint2 adm[RS][4];
#pragma unroll
    for (int rs = 0; rs < RS; ++rs)
#pragma unroll
        for (int rg = 0; rg < 4; ++rg) {
            int row = w * RW + rs * 16 + q4 * 4 + rg;
            adm[rs][rg] = *(const uint2*)&adjx[((size_t)(n0 + row) * 16 + l15) * 2];
        }

    short8 af[RS][NC];
#pragma unroll
    for (int rs = 0; rs < RS; ++rs) {
        int ar = n0 + w * RW + rs * 16 + l15;
#pragma unroll
        for (int c = 0; c < NC; ++c)
            af[rs][c] = *(const short8*)&Hhi[(size_t)ar * DK + c * 32 + q4 * 8];
    }

    // per-wave staging offsets: instruction i covers rows i*4..i*4+3 of the
    // 16-row chunk; lane l -> row i*4+(l>>4), swizzled slot (l&15)^(row&15).
    u32 goffP[4];
#pragma unroll
    for (int i = 0; i < 4; ++i) {
        int ml = i * 4 + q4;
        goffP[i] = (u32)(ml * DK + ((l15 ^ (ml & (CR - 1))) << 3));
    }

    float t0[RS][4], t1[RS][4];
#pragma unroll
    for (int rs = 0; rs < RS; ++rs)
#pragma unroll
        for (int rg = 0; rg < 4; ++rg) {
            t0[rs][rg] = __uint_as_float(NEGK);
            t1[rs][rg] = __uint_as_float(NEGK);
        }

    // prologue: stage chunk 0 into buffer 0
#pragma unroll
    for (int i = 0; i < 4; ++i)
        __builtin_amdgcn_global_load_lds(
            (const GLOBAL_AS u32*)(Hhi + goffP[i]),
            (LDS_AS u32*)&KshW[i * 512], 16, 0, 0);

    for (int it = 0; it < 64; ++it) {
        if (it < 63) {
            const u16* gp = Hhi + (size_t)(it + 1) * 16 * DK;
            int ob_ = (it + 1) & 1;
#pragma unroll
            for (int i = 0; i < 4; ++i)
                __builtin_amdgcn_global_load_lds(
                    (const GLOBAL_AS u32*)(gp + goffP[i]),
                    (LDS_AS u32*)&KshW[ob_ * PBUF + i * 512], 16, 0, 0);
            asm volatile("s_waitcnt vmcnt(4)" ::: "memory");   // current chunk landed
        } else {
            asm volatile("s_waitcnt vmcnt(0)" ::: "memory");
        }
        __builtin_amdgcn_sched_barrier(0);

        const u16* Kb = KshW + (it & 1) * PBUF;
        u32 wm[RS][4];
#pragma unroll
        for (int rs = 0; rs < RS; ++rs)
#pragma unroll
            for (int rg = 0; rg < 4; ++rg)
                wm[rs][rg] = (it & 32) ? adm[rs][rg].y : adm[rs][rg].x;

        short8 bf[NC];
#pragma unroll
        for (int c = 0; c < NC; ++c) {
            int slot = (c * 4 + q4) ^ l15;
            bf[c] = *(const short8*)&Kb[l15 * DK + slot * 8];
        }
        int jcol = it * 16 + l15;
        int bit = it & 31;
#pragma unroll
        for (int rs = 0; rs < RS; ++rs) {
            f32x4 acc = {0.f, 0.f, 0.f, 0.f};
#pragma unroll
            for (int c = 0; c < NC; ++c)
                acc = __builtin_amdgcn_mfma_f32_16x16x32_bf16(af[rs][c], bf[c], acc, 0, 0, 0);
#pragma unroll
            for (int rg = 0; rg < 4; ++rg) {
                u32 pk = (__float_as_uint(acc[rg]) & 0xFFFFFC00u) | (u32)jcol; // v_and_or
                u32 msk = (u32)__builtin_amdgcn_sbfe((int)wm[rs][rg], bit, 1);
                u32 pmu = (pk & msk) | (NEGK & ~msk);                          // v_bfi
                float tf = __uint_as_float(pmu);
                t1[rs][rg] = __builtin_amdgcn_fmed3f(tf, t0[rs][rg], t1[rs][rg]);
                t0[rs][rg] = fmaxf(t0[rs][rg], tf);
            }
        }
    }
    __syncthreads();                       // all staging dead; aliases usable
    for (int u = t; u < RT; u += 256) cnt[u] = 0;
    if (t == 0) *wln = 0;
    __syncthreads();

#pragma unroll
    for (int rs = 0; rs < RS; ++rs)
#pragma unroll
        for (int rg = 0; rg < 4; ++rg) {
            float m = t0[rs][rg];
#pragma unroll
            for (int off = 1; off < 16; off <<= 1) m = fmaxf(m, __shfl_xor(m, off));
            float thr = m - (100.0f + 0.04f * fabsf(m));
            int row = w * RW + rs * 16 + q4 * 4 + rg;
            if (t0[rs][rg] > thr) {
                int p = atomicAdd(&cnt[row], 1);
                if (p < CMAX) candm[row][p] = (int)(__float_as_uint(t0[rs][rg]) & 1023u);
            }
            if (t1[rs][rg] > thr) {
                int p = atomicAdd(&cnt[row], 1);
                if (p < CMAX) candm[row][p] = (int)(__float_as_uint(t1[rs][rg]) & 1023u);
            }
        }
    __syncthreads();

    // compact (row,ci) worklist
    if (t < RT) {
        int kc = cnt[t]; if (kc > CMAX) kc = CMAX;
        int base = atomicAdd(wln, kc);
        for (int i = 0; i < kc; ++i) wl[base + i] = (t << 4) | i;
    }
    __syncthreads();

    // exact fp32 dots: one 8-lane group per candidate, coalesced 128B segments
    {
        int M = *wln;
        int g = t >> 3, l = t & 7;
        for (int e = g; e < M; e += 32) {
            int pk = wl[e];
            int row = pk >> 4, ci = pk & 15;
            const float* qa = Hf + (size_t)(n0 + row) * DK + l * (DK / 8);
            const float* kb = Hf + (size_t)candm[row][ci] * DK + l * (DK / 8);
            float acc = 0.f;
#pragma unroll
            for (int d = 0; d < DK / 8; d += 4) {
                float4 a  = *(const float4*)&qa[d];
                float4 bv = *(const float4*)&kb[d];
                acc += a.x * bv.x + a.y * bv.y + a.z * bv.z + a.w * bv.w;
            }
            acc += __shfl_xor(acc, 4);
            acc += __shfl_xor(acc, 2);
            acc += __shfl_xor(acc, 1);
            if (l == 0) cands[row][ci] = acc;
        }
    }
    __syncthreads();

    for (int row = t; row < RT; row += 256) {
        int kc = cnt[row]; if (kc > CMAX) kc = CMAX;
        float M = -3e38f;
        for (int i = 0; i < kc; ++i) M = fmaxf(M, cands[row][i]);
        float L = 0.f;
        for (int i = 0; i < kc; ++i) { float p = expf(cands[row][i] - M); cands[row][i] = p; L += p; }
        float inv = 1.f / L;
        for (int i = 0; i < kc; ++i) cands[row][i] *= inv;
    }
    __syncthreads();

    constexpr int D4 = DK / 4;
    for (int e = t; e < RT * D4; e += 256) {
        int row = e / D4, d4 = (e % D4) * 4;
        int kc = cnt[row]; if (kc > CMAX) kc = CMAX;
        float4 o = *(const float4*)&bs[d4];
        for (int i = 0; i < kc; ++i) {
            float p = cands[row][i];
            const float4 hv = *(const float4*)&Hf[(size_t)candm[row][i] * DK + d4];
            o.x += p * hv.x; o.y += p * hv.y; o.z += p * hv.z; o.w += p * hv.w;
        }
        o.x = o.x > 0.f ? o.x : 0.01f * o.x;
        o.y = o.y > 0.f ? o.y : 0.01f * o.y;
        o.z = o.z > 0.f ? o.z : 0.01f * o.z;
        o.w = o.w > 0.f ? o.w : 0.01f * o.w;
        *(float4*)&ob[(size_t)(n0 + row) * ORS + d4] = o;
    }
}

// ---------------------------------------------------------------- K4: L2 fused masked attention
__global__ __launch_bounds__(256) void attn6w(const u16* __restrict__ hhi,
                                              const float* __restrict__ hf,
                                              const u32* __restrict__ adjx,
                                              const float* __restrict__ bias,
                                              float* __restrict__ outp) {
    constexpr int DK = 64, NC = 2, CMAX = 16;
    constexpr int QR = 128;
    constexpr int HBUF = QR * DK;
    const u32 NEGK = 0xFF800000u;

    int bx = blockIdx.x;
    int b = bx & 15, tile = bx >> 4;
    int n0 = tile * 64;
    const u16*   Hhi = hhi + (size_t)b * 1024 * DK;
    const float* Hf  = hf  + (size_t)b * 1024 * DK;
    float* ob = outp + (size_t)b * 1024 * 64;

    __shared__ __attribute__((aligned(16))) u16 Ksh[2 * HBUF];
    int   (*candm)[CMAX] = (int(*)[CMAX])Ksh;                // 4 KB @ 0
    float (*cands)[CMAX] = (float(*)[CMAX])(Ksh + 2048);     // 4 KB @ 4K
    int* cnt = (int*)(Ksh + 4096);                           // 256 B @ 8K
    int* wl  = (int*)(Ksh + 4224);                           // 4 KB @ 8.25K
    int* wln = (int*)(Ksh + 6272);                           // 4 B @ 12.25K

    int t = threadIdx.x, lane = t & 63, w = t >> 6;
    int l15 = lane & 15, q4 = lane >> 4;

    uint2 adm[4];
#pragma unroll
    for (int rg = 0; rg < 4; ++rg) {
        int row = w * 16 + q4 * 4 + rg;
        adm[rg] = *(const uint2*)&adjx[((size_t)(n0 + row) * 16 + l15) * 2];
    }

    short8 af[NC];
    {
        int ar = n0 + w * 16 + l15;
#pragma unroll
        for (int c = 0; c < NC; ++c)
            af[c] = *(const short8*)&Hhi[(size_t)ar * DK + c * 32 + q4 * 8];
    }

    u32 goff[4];
#pragma unroll
    for (int i = 0; i < 4; ++i) {
        int q = i * 64 + lane;
        int lr = w * 32 + (q >> 3);
        int sl = q & 7;
        goff[i] = (u32)(lr * DK + ((sl ^ (lr & 7)) << 3));
    }

    float t0[4], t1[4];
#pragma unroll
    for (int rg = 0; rg < 4; ++rg) { t0[rg] = __uint_as_float(NEGK); t1[rg] = __uint_as_float(NEGK); }

#pragma unroll
    for (int i = 0; i < 4; ++i)
        __builtin_amdgcn_global_load_lds(
            (const GLOBAL_AS u32*)(Hhi + goff[i]),
            (LDS_AS u32*)&Ksh[w * 32 * DK + i * 512], 16, 0, 0);

    for (int s = 0; s < 8; ++s) {
        __syncthreads();
        if (s < 7) {
            const u16* gp = Hhi + (size_t)(s + 1) * QR * DK;
            int obuf = (s + 1) & 1;
#pragma unroll
            for (int i = 0; i < 4; ++i)
                __builtin_amdgcn_global_load_lds(
                    (const GLOBAL_AS u32*)(gp + goff[i]),
                    (LDS_AS u32*)&Ksh[obuf * HBUF + w * 32 * DK + i * 512], 16, 0, 0);
        }
        const u16* Kb = Ksh + (s & 1) * HBUF;
#pragma unroll
        for (int mq = 0; mq < 2; ++mq) {
            int m0 = s * QR + mq * 64;
            int J0 = m0 >> 4, shb = J0 & 31;
            u32 wmsel[4];
#pragma unroll
            for (int rg = 0; rg < 4; ++rg) wmsel[rg] = (J0 & 32) ? adm[rg].y : adm[rg].x;
#pragma unroll
            for (int mt = 0; mt < 4; ++mt) {
                int mloc = mq * 64 + mt * 16 + l15;
                short8 bf[NC];
#pragma unroll
                for (int c = 0; c < NC; ++c) {
                    int slot = (c * 4 + q4) ^ (mloc & 7);
                    bf[c] = *(const short8*)&Kb[mloc * DK + slot * 8];
                }
                int jcol = m0 + mt * 16 + l15;
                f32x4 acc = {0.f, 0.f, 0.f, 0.f};
#pragma unroll
                for (int c = 0; c < NC; ++c)
                    acc = __builtin_amdgcn_mfma_f32_16x16x32_bf16(af[c], bf[c], acc, 0, 0, 0);
#pragma unroll
                for (int rg = 0; rg < 4; ++rg) {
                    u32 pk = (__float_as_uint(acc[rg]) & 0xFFFFFC00u) | (u32)jcol;
                    u32 msk = (u32)__builtin_amdgcn_sbfe((int)wmsel[rg], shb + mt, 1);
                    u32 pmu = (pk & msk) | (NEGK & ~msk);
                    float tf = __uint_as_float(pmu);
                    t1[rg] = __builtin_amdgcn_fmed3f(tf, t0[rg], t1[rg]);
                    t0[rg] = fmaxf(t0[rg], tf);
                }
            }
        }
    }
    __syncthreads();
    if (t < 64) cnt[t] = 0;
    if (t == 0) *wln = 0;
    __syncthreads();

#pragma unroll
    for (int rg = 0; rg < 4; ++rg) {
        float m = t0[rg];
#pragma unroll
        for (int off = 1; off < 16; off <<= 1) m = fmaxf(m, __shfl_xor(m, off));
        float thr = m - (100.0f + 0.04f * fabsf(m));
        int row = w * 16 + q4 * 4 + rg;
        if (t0[rg] > thr) {
            int p = atomicAdd(&cnt[row], 1);
            if (p < CMAX) candm[row][p] = (int)(__float_as_uint(t0[rg]) & 1023u);
        }
        if (t1[rg] > thr) {
            int p = atomicAdd(&cnt[row], 1);
            if (p < CMAX) candm[row][p] = (int)(__float_as_uint(t1[rg]) & 1023u);
        }
    }
    __syncthreads();

    // compact (row,ci) worklist
    if (t < 64) {
        int kc = cnt[t]; if (kc > CMAX) kc = CMAX;
        int base = atomicAdd(wln, kc);
        for (int i = 0; i < kc; ++i) wl[base + i] = (t << 4) | i;
    }
    __syncthreads();

    // exact fp32 dots: one 8-lane group per candidate
    {
        int M = *wln;
        int g = t >> 3, l = t & 7;
        for (int e = g; e < M; e += 32) {
            int pk = wl[e];
            int row = pk >> 4, ci = pk & 15;
            const float* qa = Hf + (size_t)(n0 + row) * DK + l * (DK / 8);
            const float* kb = Hf + (size_t)candm[row][ci] * DK + l * (DK / 8);
            float acc = 0.f;
#pragma unroll
            for (int d = 0; d < DK / 8; d += 4) {
                float4 a  = *(const float4*)&qa[d];
                float4 bv = *(const float4*)&kb[d];
                acc += a.x * bv.x + a.y * bv.y + a.z * bv.z + a.w * bv.w;
            }
            acc += __shfl_xor(acc, 4);
            acc += __shfl_xor(acc, 2);
            acc += __shfl_xor(acc, 1);
            if (l == 0) cands[row][ci] = acc;
        }
    }
    __syncthreads();

    if (t < 64) {
        int row = t;
        int kc = cnt[row]; if (kc > CMAX) kc = CMAX;
        float M = -3e38f;
        for (int i = 0; i < kc; ++i) M = fmaxf(M, cands[row][i]);
        float L = 0.f;
        for (int i = 0; i < kc; ++i) { float p = expf(cands[row][i] - M); cands[row][i] = p; L += p; }
        float inv = 1.f / L;
        for (int i = 0; i < kc; ++i) cands[row][i] *= inv;
    }
    __syncthreads();

    for (int e = t; e < 64 * 16; e += 256) {
        int row = e / 16, d4 = (e % 16) * 4;
        int kc = cnt[row]; if (kc > CMAX) kc = CMAX;
        float4 o = *(const float4*)&bias[d4];
        for (int i = 0; i < kc; ++i) {
            float p = cands[row][i];
            const float4 hv = *(const float4*)&Hf[(size_t)candm[row][i] * DK + d4];
            o.x += p * hv.x; o.y += p * hv.y; o.z += p * hv.z; o.w += p * hv.w;
        }
        o.x = o.x > 0.f ? o.x : 0.01f * o.x;
        o.y = o.y > 0.f ? o.y : 0.01f * o.y;
        o.z = o.z > 0.f ? o.z : 0.01f * o.z;
        o.w = o.w > 0.f ? o.w : 0.01f * o.w;
        *(float4*)&ob[(size_t)(n0 + row) * 64 + d4] = o;
    }
}

// ---------------------------------------------------------------- launcher
extern "C" void kernel_launch(void* const* d_in, const int* in_sizes, int n_in,
                              void* d_out, int out_size, void* d_ws, size_t ws_size,
                              hipStream_t stream) {
    (void)in_sizes; (void)n_in; (void)out_size; (void)ws_size;
    const float* flow_x = (const float*)d_in[0];   // [16,1024,64]
    const float* graph  = (const float*)d_in[1];   // [1024,1024]
    const float* Wh     = (const float*)d_in[2];   // [8,64,128]
    const float* bh     = (const float*)d_in[3];   // [8,128]
    const float* W_out  = (const float*)d_in[4];   // [1024,64]
    const float* b_out  = (const float*)d_in[5];   // [64]
    float* out = (float*)d_out;                    // [16,1024,64] fp32

    // workspace carve-up (~178 MB; all 16B-aligned)
    float* h_f32 = (float*)d_ws;                       // 16,777,216 f  [bh][n][128]
    float* x2    = h_f32 + 16777216;                   // 16,777,216 f  [b][n][1024]
    float* h2    = x2 + 16777216;                      //  1,048,576 f  [b][n][64]
    u16*  h_hi   = (u16*)(h2 + 1048576);               // 16,777,216 u16
    u16*  h2_hi  = h_hi + 16777216;                    //  1,048,576 u16
    u32*  adjx   = (u32*)(h2_hi + 1048576);            //     32,768 u32 (residue-bucketed)
    // proj2 partials (8 x 1,048,576 f) alias h_f32 — dead after attn6.
    float* ps    = h_f32;

    pack_adj3<<<1024, 256, 0, stream>>>(graph, adjx);
    proj1<<<dim3(128, 8), 256, 0, stream>>>(flow_x, Wh, h_f32, h_hi);
    attn6<128, 8, 1024, 128><<<1024, 256, 0, stream>>>(h_hi, h_f32, adjx, bh, x2);
    proj2p<<<dim3(16, 8, 8), 256, 0, stream>>>(x2, W_out, ps);
    reduce2<<<1024, 256, 0, stream>>>(ps, h2, h2_hi);
    attn6w<<<256, 256, 0, stream>>>(h2_hi, h2, adjx, b_out, out);
}

// Round 4
// 244.776 us; speedup vs baseline: 1.1037x; 1.1037x over previous
//
#include <hip/hip_runtime.h>
#include <cstdint>
#include <cstddef>

// GATNet on MI355X — round 17.
// Round-16's proj2m (bf16 hi/lo MFMA GEMM, 3 products) failed absmax 25 vs
// 19.76: h2 rel error ~2^-17 perturbed attn6w's exact-refinement logits
// (|logit|~1e5-1e6) by O(10-100) -> softmax near-tie flips. Round-17 keeps
// the structure but uses a 3-WAY bf16 split of BOTH operands (24 mantissa
// bits each) and the 6 products >= 2^-24:
//   h2 ~= AhBh + AhBm + AmBh + AhBl + AmBm + AlBh   (rel err ~2^-24 ~ fp32)
// All residual subtractions are exact in fp32 (Sterbenz). attn6 = proven
// round-14 version (94.6us). proj2p/reduce2 (split-K + 64MB round-trip)
// remain eliminated.

typedef short short8 __attribute__((ext_vector_type(8)));
typedef float f32x4  __attribute__((ext_vector_type(4)));
typedef unsigned short u16;
typedef unsigned char  u8;
typedef unsigned int   u32;

#define GLOBAL_AS __attribute__((address_space(1)))
#define LDS_AS    __attribute__((address_space(3)))

__device__ __forceinline__ u16 f2bf(float f) {        // RNE float->bf16 bits
    u32 x = __float_as_uint(f);
    u32 r = (x + 0x7FFFu + ((x >> 16) & 1u)) >> 16;
    return (u16)r;
}

// ---------------------------------------------------------------- K0: graph -> residue-bucketed bitmasks
__global__ __launch_bounds__(256) void pack_adj3(const float* __restrict__ g,
                                                 u32* __restrict__ adjx) {
    int n = blockIdx.x, t = threadIdx.x;
    __shared__ u8 bits[1024];
    float4 v = *(const float4*)&g[(size_t)n * 1024 + t * 4];
    bits[t * 4 + 0] = v.x != 0.0f;
    bits[t * 4 + 1] = v.y != 0.0f;
    bits[t * 4 + 2] = v.z != 0.0f;
    bits[t * 4 + 3] = v.w != 0.0f;
    __syncthreads();
    if (t < 32) {
        int r = t >> 1, h = t & 1;
        u32 wd = 0;
#pragma unroll
        for (int j = 0; j < 32; ++j)
            wd |= (u32)bits[16 * (h * 32 + j) + r] << j;
        adjx[((size_t)n * 16 + r) * 2 + h] = wd;
    }
}

// ---------------------------------------------------------------- K1: h = x @ Wh  (fp32 exact + bf16-hi copy)
__global__ __launch_bounds__(256) void proj1(const float* __restrict__ x,
                                             const float* __restrict__ Whg,
                                             float* __restrict__ hf,
                                             u16* __restrict__ hhi) {
    int bh = blockIdx.x;                 // b*8+hd
    int hd = bh & 7, bb = bh >> 3;
    int n0 = blockIdx.y * 128;
    const float* W  = Whg + (size_t)hd * 64 * 128;
    const float* xb = x + ((size_t)bb * 1024 + n0) * 64;
    __shared__ __attribute__((aligned(16))) float ws[32][132];
    __shared__ __attribute__((aligned(16))) float xsT[32][132];
    int t = threadIdx.x;
    int rg = t >> 4, cg = t & 15;
    int r0 = rg * 8, c0 = cg * 8;
    float acc[8][8] = {};
    for (int kt = 0; kt < 2; ++kt) {
        int kb = kt * 32;
        for (int u = t; u < 1024; u += 256) {
            int k = u >> 5, d4 = (u & 31) << 2;
            *(float4*)&ws[k][d4] = *(const float4*)&W[(size_t)(kb + k) * 128 + d4];
        }
        for (int u = t; u < 1024; u += 256) {
            int r = u >> 3, k4 = (u & 7) << 2;
            float4 xv = *(const float4*)&xb[(size_t)r * 64 + kb + k4];
            xsT[k4 + 0][r] = xv.x; xsT[k4 + 1][r] = xv.y;
            xsT[k4 + 2][r] = xv.z; xsT[k4 + 3][r] = xv.w;
        }
        __syncthreads();
        for (int k = 0; k < 32; ++k) {
            float4 xa = *(float4*)&xsT[k][r0];
            float4 xbv = *(float4*)&xsT[k][r0 + 4];
            float4 wa = *(float4*)&ws[k][c0];
            float4 wb = *(float4*)&ws[k][c0 + 4];
            float xq[8] = {xa.x, xa.y, xa.z, xa.w, xbv.x, xbv.y, xbv.z, xbv.w};
            float wv[8] = {wa.x, wa.y, wa.z, wa.w, wb.x, wb.y, wb.z, wb.w};
#pragma unroll
            for (int i = 0; i < 8; ++i)
#pragma unroll
                for (int j = 0; j < 8; ++j)
                    acc[i][j] = fmaf(xq[i], wv[j], acc[i][j]);
        }
        __syncthreads();
    }
#pragma unroll
    for (int i = 0; i < 8; ++i) {
        int n = n0 + r0 + i;
        size_t base = ((size_t)bh * 1024 + n) * 128 + c0;
        float4 f0 = {acc[i][0], acc[i][1], acc[i][2], acc[i][3]};
        float4 f1 = {acc[i][4], acc[i][5], acc[i][6], acc[i][7]};
        *(float4*)&hf[base]     = f0;
        *(float4*)&hf[base + 4] = f1;
        uint4 up;
        up.x = (u32)f2bf(acc[i][0]) | ((u32)f2bf(acc[i][1]) << 16);
        up.y = (u32)f2bf(acc[i][2]) | ((u32)f2bf(acc[i][3]) << 16);
        up.z = (u32)f2bf(acc[i][4]) | ((u32)f2bf(acc[i][5]) << 16);
        up.w = (u32)f2bf(acc[i][6]) | ((u32)f2bf(acc[i][7]) << 16);
        *(uint4*)&hhi[base] = up;
    }
}

// ---------------------------------------------------------------- K3a: W_out -> MFMA-fragment-ordered bf16 h/m/l
// frag group g = (c*32 + s)*64 + lane; element j of group g is
// W[(s*32 + (lane>>4)*8 + j)][c*16 + (lane&15)]  (B^T[col][k] 3-way split).
__global__ __launch_bounds__(256) void wcvt(const float* __restrict__ Wo,
                                            u16* __restrict__ wfh,
                                            u16* __restrict__ wfm,
                                            u16* __restrict__ wfl) {
    int g = blockIdx.x * 256 + threadIdx.x;      // 8192 groups, 32 blocks
    int lane = g & 63, s = (g >> 6) & 31, c = g >> 11;
    int col = c * 16 + (lane & 15);
    int k0 = s * 32 + (lane >> 4) * 8;
    u32 hp[4], mp[4], lp[4];
#pragma unroll
    for (int jj = 0; jj < 4; ++jj) {
        float x0 = Wo[(size_t)(k0 + jj * 2 + 0) * 64 + col];
        float x1 = Wo[(size_t)(k0 + jj * 2 + 1) * 64 + col];
        u16 h0 = f2bf(x0), h1 = f2bf(x1);
        float r0 = x0 - __uint_as_float((u32)h0 << 16);
        float r1 = x1 - __uint_as_float((u32)h1 << 16);
        u16 m0 = f2bf(r0), m1 = f2bf(r1);
        float s0 = r0 - __uint_as_float((u32)m0 << 16);
        float s1 = r1 - __uint_as_float((u32)m1 << 16);
        u16 l0 = f2bf(s0), l1 = f2bf(s1);
        hp[jj] = (u32)h0 | ((u32)h1 << 16);
        mp[jj] = (u32)m0 | ((u32)m1 << 16);
        lp[jj] = (u32)l0 | ((u32)l1 << 16);
    }
    uint4 hv = {hp[0], hp[1], hp[2], hp[3]};
    uint4 mv = {mp[0], mp[1], mp[2], mp[3]};
    uint4 lv = {lp[0], lp[1], lp[2], lp[3]};
    *(uint4*)&wfh[(size_t)g * 8] = hv;
    *(uint4*)&wfm[(size_t)g * 8] = mv;
    *(uint4*)&wfl[(size_t)g * 8] = lv;
}

// ---------------------------------------------------------------- K3b: h2 = x2 @ W_out via 3-way bf16 MFMA
// 512 blocks (16 b x 32 row-tiles of 32), 256 thr / 4 waves.
// Wave w: rowfrag rf=w&1 (16 rows), colfrags {cs*2, cs*2+1} (cs=w>>1).
// K-loop: 32 steps of 32. A staged fp32->h/m/l in LDS (2-deep reg lookahead);
// B read directly from frag-ordered wfh/wfm/wfl (coalesced, L2-resident).
// 6 products per colfrag: hh + hm + mh + hl + mm + lh  (rel err ~2^-24).
__global__ __launch_bounds__(256) void proj2m(const float* __restrict__ x2,
                                              const u16* __restrict__ wfh,
                                              const u16* __restrict__ wfm,
                                              const u16* __restrict__ wfl,
                                              float* __restrict__ h2f,
                                              u16* __restrict__ h2hi) {
    int bx = blockIdx.x;
    int b = bx & 15, tile = bx >> 4;
    int n0 = tile * 32;
    const float* X = x2 + ((size_t)b * 1024 + n0) * 1024;

    __shared__ __attribute__((aligned(16))) u16 Ah[2][32][40];   // +8 pad
    __shared__ __attribute__((aligned(16))) u16 Am[2][32][40];
    __shared__ __attribute__((aligned(16))) u16 Al[2][32][40];

    int t = threadIdx.x, lane = t & 63, w = t >> 6;
    int l15 = lane & 15, q4 = lane >> 4;
    int rf = w & 1, cs = w >> 1;
    int rstage = t >> 3, kseg = t & 7;

    f32x4 acc0 = {0.f, 0.f, 0.f, 0.f}, acc1 = {0.f, 0.f, 0.f, 0.f};

    auto stage = [&](int buf, const float4& xv) {
        float xs[4] = {xv.x, xv.y, xv.z, xv.w};
        u16 hh[4], mm_[4], ll[4];
#pragma unroll
        for (int j = 0; j < 4; ++j) {
            u16 h = f2bf(xs[j]);
            float r1 = xs[j] - __uint_as_float((u32)h << 16);
            u16 m = f2bf(r1);
            float r2 = r1 - __uint_as_float((u32)m << 16);
            u16 l = f2bf(r2);
            hh[j] = h; mm_[j] = m; ll[j] = l;
        }
        uint2 hp = {(u32)hh[0] | ((u32)hh[1] << 16), (u32)hh[2] | ((u32)hh[3] << 16)};
        uint2 mp = {(u32)mm_[0] | ((u32)mm_[1] << 16), (u32)mm_[2] | ((u32)mm_[3] << 16)};
        uint2 lp = {(u32)ll[0] | ((u32)ll[1] << 16), (u32)ll[2] | ((u32)ll[3] << 16)};
        *(uint2*)&Ah[buf][rstage][kseg * 4] = hp;
        *(uint2*)&Am[buf][rstage][kseg * 4] = mp;
        *(uint2*)&Al[buf][rstage][kseg * 4] = lp;
    };

    float4 xv0 = *(const float4*)&X[(size_t)rstage * 1024 + kseg * 4];
    stage(0, xv0);
    float4 xva = *(const float4*)&X[(size_t)rstage * 1024 + 32 + kseg * 4];
    float4 xvb = *(const float4*)&X[(size_t)rstage * 1024 + 64 + kseg * 4];

    for (int s = 0; s < 32; ++s) {
        __syncthreads();                   // tile s staged & visible
        int buf = s & 1;
        if (s < 31) {
            stage(buf ^ 1, xva);           // stage tile s+1
            xva = xvb;
            if (s < 30)
                xvb = *(const float4*)&X[(size_t)rstage * 1024 + (s + 3) * 32 + kseg * 4];
        }
        short8 ah = *(const short8*)&Ah[buf][rf * 16 + l15][q4 * 8];
        short8 am = *(const short8*)&Am[buf][rf * 16 + l15][q4 * 8];
        short8 al = *(const short8*)&Al[buf][rf * 16 + l15][q4 * 8];
        size_t f0 = ((size_t)((cs * 2 + 0) * 32 + s) * 64 + lane) * 8;
        size_t f1 = ((size_t)((cs * 2 + 1) * 32 + s) * 64 + lane) * 8;
        short8 bh0 = *(const short8*)&wfh[f0];
        short8 bm0 = *(const short8*)&wfm[f0];
        short8 bl0 = *(const short8*)&wfl[f0];
        short8 bh1 = *(const short8*)&wfh[f1];
        short8 bm1 = *(const short8*)&wfm[f1];
        short8 bl1 = *(const short8*)&wfl[f1];
        acc0 = __builtin_amdgcn_mfma_f32_16x16x32_bf16(ah, bh0, acc0, 0, 0, 0);
        acc0 = __builtin_amdgcn_mfma_f32_16x16x32_bf16(ah, bm0, acc0, 0, 0, 0);
        acc0 = __builtin_amdgcn_mfma_f32_16x16x32_bf16(am, bh0, acc0, 0, 0, 0);
        acc0 = __builtin_amdgcn_mfma_f32_16x16x32_bf16(ah, bl0, acc0, 0, 0, 0);
        acc0 = __builtin_amdgcn_mfma_f32_16x16x32_bf16(am, bm0, acc0, 0, 0, 0);
        acc0 = __builtin_amdgcn_mfma_f32_16x16x32_bf16(al, bh0, acc0, 0, 0, 0);
        acc1 = __builtin_amdgcn_mfma_f32_16x16x32_bf16(ah, bh1, acc1, 0, 0, 0);
        acc1 = __builtin_amdgcn_mfma_f32_16x16x32_bf16(ah, bm1, acc1, 0, 0, 0);
        acc1 = __builtin_amdgcn_mfma_f32_16x16x32_bf16(am, bh1, acc1, 0, 0, 0);
        acc1 = __builtin_amdgcn_mfma_f32_16x16x32_bf16(ah, bl1, acc1, 0, 0, 0);
        acc1 = __builtin_amdgcn_mfma_f32_16x16x32_bf16(am, bm1, acc1, 0, 0, 0);
        acc1 = __builtin_amdgcn_mfma_f32_16x16x32_bf16(al, bh1, acc1, 0, 0, 0);
    }

    // C frag: col = lane&15, row = q4*4 + i
#pragma unroll
    for (int i = 0; i < 4; ++i) {
        int row = n0 + rf * 16 + q4 * 4 + i;
        size_t a0 = ((size_t)b * 1024 + row) * 64 + (cs * 2 + 0) * 16 + l15;
        size_t a1 = ((size_t)b * 1024 + row) * 64 + (cs * 2 + 1) * 16 + l15;
        h2f[a0] = acc0[i];  h2hi[a0] = f2bf(acc0[i]);
        h2f[a1] = acc1[i];  h2hi[a1] = f2bf(acc1[i]);
    }
}

// ---------------------------------------------------------------- K2: L1 fused masked attention (round-14 version)
// 32768 B LDS (cnt/worklist aliased into staging region) + __launch_bounds__(256,4).
template <int DK, int NH, int ORS, int RT>
__global__ __launch_bounds__(256, 4) void attn6(const u16* __restrict__ hhi,
                                                const float* __restrict__ hf,
                                                const u32* __restrict__ adjx,
                                                const float* __restrict__ bias,
                                                float* __restrict__ outp) {
    constexpr int CR   = DK / 8;
    constexpr int NC   = DK / 32;
    constexpr int LGCR = (CR == 16) ? 4 : 3;
    constexpr int RPI  = 64 / CR;
    constexpr int NI   = 16 / RPI;
    constexpr int RW   = RT / 4;
    constexpr int RS   = RW / 16;
    constexpr int NBH  = NH * 16;
    constexpr int CMAX = 16;
    constexpr int HBUF = 64 * DK;         // u16 per staging buffer
    const u32 NEGK = 0xFF800000u;

    int bx = blockIdx.x;
    int bh = bx % NBH, tile = bx / NBH;   // XCD swizzle: bx%8 == bh%8
    int hd = (NH == 1) ? 0 : (bh & (NH - 1));
    int b  = (NH == 1) ? bh : (bh >> 3);
    int n0 = tile * RT;
    const u16*   Hhi = hhi + (size_t)bh * 1024 * DK;
    const float* Hf  = hf  + (size_t)bh * 1024 * DK;
    const float* bs  = bias + (size_t)hd * DK;
    float* ob = outp + (size_t)b * 1024 * ORS + (size_t)hd * DK;

    // LDS = exactly 2 x 16 KB staging buffers; cand arrays + cnt + worklist
    // alias them (all staging dead after the post-loop barrier).
    __shared__ __attribute__((aligned(16))) char smem[2 * HBUF * 2];   // 32768 B
    u16* Ksh = (u16*)smem;
    int   (*candm)[CMAX] = (int(*)[CMAX])smem;               // 8 KB @ 0
    float (*cands)[CMAX] = (float(*)[CMAX])(smem + 8192);    // 8 KB @ 8K
    int*   cnt           = (int*)(smem + 16384);             // 512 B @ 16K
    int*   wl            = (int*)(smem + 16896);             // 8 KB @ 16.5K
    int*   wln           = (int*)(smem + 25088);             // 4 B

    int t = threadIdx.x, lane = t & 63, w = t >> 6;
    int l15 = lane & 15, q4 = lane >> 4;

    uint2 adm[RS][4];
#pragma unroll
    for (int rs = 0; rs < RS; ++rs)
#pragma unroll
        for (int rg = 0; rg < 4; ++rg) {
            int row = w * RW + rs * 16 + q4 * 4 + rg;
            adm[rs][rg] = *(const uint2*)&adjx[((size_t)(n0 + row) * 16 + l15) * 2];
        }

    short8 af[RS][NC];
#pragma unroll
    for (int rs = 0; rs < RS; ++rs) {
        int ar = n0 + w * RW + rs * 16 + l15;
#pragma unroll
        for (int c = 0; c < NC; ++c)
            af[rs][c] = *(const short8*)&Hhi[(size_t)ar * DK + c * 32 + q4 * 8];
    }

    int mb = w * 16 + (lane >> LGCR);
    int sl = lane & (CR - 1);
    u32 goff[NI];
#pragma unroll
    for (int i = 0; i < NI; ++i) {
        int m = mb + i * RPI;
        goff[i] = (u32)(m * DK + ((sl ^ (m & (CR - 1))) << 3));
    }

    float t0[RS][4], t1[RS][4];
#pragma unroll
    for (int rs = 0; rs < RS; ++rs)
#pragma unroll
        for (int rg = 0; rg < 4; ++rg) {
            t0[rs][rg] = __uint_as_float(NEGK);
            t1[rs][rg] = __uint_as_float(NEGK);
        }

    {
        const u16* gp = Hhi;
#pragma unroll
        for (int i = 0; i < NI; ++i)
            __builtin_amdgcn_global_load_lds(
                (const GLOBAL_AS u32*)(gp + goff[i]),
                (LDS_AS u32*)&Ksh[w * 16 * DK + i * 512], 16, 0, 0);
    }
    for (int m0 = 0; m0 < 1024; m0 += 64) {
        int buf = (m0 >> 6) & 1;
        __syncthreads();
        if (m0 + 64 < 1024) {
            const u16* gp = Hhi + (size_t)(m0 + 64) * DK;
#pragma unroll
            for (int i = 0; i < NI; ++i)
                __builtin_amdgcn_global_load_lds(
                    (const GLOBAL_AS u32*)(gp + goff[i]),
                    (LDS_AS u32*)&Ksh[(buf ^ 1) * HBUF + w * 16 * DK + i * 512], 16, 0, 0);
        }
        const u16* Kb = Ksh + buf * HBUF;
        int J0 = m0 >> 4, shb = J0 & 31;
        u32 wmsel[RS][4];
#pragma unroll
        for (int rs = 0; rs < RS; ++rs)
#pragma unroll
            for (int rg = 0; rg < 4; ++rg)
                wmsel[rs][rg] = (J0 & 32) ? adm[rs][rg].y : adm[rs][rg].x;
#pragma unroll
        for (int mt = 0; mt < 4; ++mt) {
            int mrow = mt * 16 + l15;
            short8 bf[NC];
#pragma unroll
            for (int c = 0; c < NC; ++c) {
                int slot = (c * 4 + q4) ^ (mrow & (CR - 1));
                bf[c] = *(const short8*)&Kb[mrow * DK + slot * 8];
            }
            int jcol = m0 + mt * 16 + l15;
#pragma unroll
            for (int rs = 0; rs < RS; ++rs) {
                f32x4 acc = {0.f, 0.f, 0.f, 0.f};
#pragma unroll
                for (int c = 0; c < NC; ++c)
                    acc = __builtin_amdgcn_mfma_f32_16x16x32_bf16(af[rs][c], bf[c], acc, 0, 0, 0);
#pragma unroll
                for (int rg = 0; rg < 4; ++rg) {
                    u32 pk = (__float_as_uint(acc[rg]) & 0xFFFFFC00u) | (u32)jcol; // v_and_or
                    u32 msk = (u32)__builtin_amdgcn_sbfe((int)wmsel[rs][rg], shb + mt, 1);
                    u32 pmu = (pk & msk) | (NEGK & ~msk);                          // v_bfi
                    float tf = __uint_as_float(pmu);
                    t1[rs][rg] = __builtin_amdgcn_fmed3f(tf, t0[rs][rg], t1[rs][rg]);
                    t0[rs][rg] = fmaxf(t0[rs][rg], tf);
                }
            }
        }
    }
    __syncthreads();                       // all staging dead; aliases usable
    for (int u = t; u < RT; u += 256) cnt[u] = 0;
    if (t == 0) *wln = 0;
    __syncthreads();

#pragma unroll
    for (int rs = 0; rs < RS; ++rs)
#pragma unroll
        for (int rg = 0; rg < 4; ++rg) {
            float m = t0[rs][rg];
#pragma unroll
            for (int off = 1; off < 16; off <<= 1) m = fmaxf(m, __shfl_xor(m, off));
            float thr = m - (100.0f + 0.04f * fabsf(m));
            int row = w * RW + rs * 16 + q4 * 4 + rg;
            if (t0[rs][rg] > thr) {
                int p = atomicAdd(&cnt[row], 1);
                if (p < CMAX) candm[row][p] = (int)(__float_as_uint(t0[rs][rg]) & 1023u);
            }
            if (t1[rs][rg] > thr) {
                int p = atomicAdd(&cnt[row], 1);
                if (p < CMAX) candm[row][p] = (int)(__float_as_uint(t1[rs][rg]) & 1023u);
            }
        }
    __syncthreads();

    // compact (row,ci) worklist
    if (t < RT) {
        int kc = cnt[t]; if (kc > CMAX) kc = CMAX;
        int base = atomicAdd(wln, kc);
        for (int i = 0; i < kc; ++i) wl[base + i] = (t << 4) | i;
    }
    __syncthreads();

    // exact fp32 dots: one 8-lane group per candidate, coalesced 128B segments
    {
        int M = *wln;
        int g = t >> 3, l = t & 7;
        for (int e = g; e < M; e += 32) {
            int pk = wl[e];
            int row = pk >> 4, ci = pk & 15;
            const float* qa = Hf + (size_t)(n0 + row) * DK + l * (DK / 8);
            const float* kb = Hf + (size_t)candm[row][ci] * DK + l * (DK / 8);
            float acc = 0.f;
#pragma unroll
            for (int d = 0; d < DK / 8; d += 4) {
                float4 a  = *(const float4*)&qa[d];
                float4 bv = *(const float4*)&kb[d];
                acc += a.x * bv.x + a.y * bv.y + a.z * bv.z + a.w * bv.w;
            }
            acc += __shfl_xor(acc, 4);
            acc += __shfl_xor(acc, 2);
            acc += __shfl_xor(acc, 1);
            if (l == 0) cands[row][ci] = acc;
        }
    }
    __syncthreads();

    for (int row = t; row < RT; row += 256) {
        int kc = cnt[row]; if (kc > CMAX) kc = CMAX;
        float M = -3e38f;
        for (int i = 0; i < kc; ++i) M = fmaxf(M, cands[row][i]);
        float L = 0.f;
        for (int i = 0; i < kc; ++i) { float p = expf(cands[row][i] - M); cands[row][i] = p; L += p; }
        float inv = 1.f / L;
        for (int i = 0; i < kc; ++i) cands[row][i] *= inv;
    }
    __syncthreads();

    constexpr int D4 = DK / 4;
    for (int e = t; e < RT * D4; e += 256) {
        int row = e / D4, d4 = (e % D4) * 4;
        int kc = cnt[row]; if (kc > CMAX) kc = CMAX;
        float4 o = *(const float4*)&bs[d4];
        for (int i = 0; i < kc; ++i) {
            float p = cands[row][i];
            const float4 hv = *(const float4*)&Hf[(size_t)candm[row][i] * DK + d4];
            o.x += p * hv.x; o.y += p * hv.y; o.z += p * hv.z; o.w += p * hv.w;
        }
        o.x = o.x > 0.f ? o.x : 0.01f * o.x;
        o.y = o.y > 0.f ? o.y : 0.01f * o.y;
        o.z = o.z > 0.f ? o.z : 0.01f * o.z;
        o.w = o.w > 0.f ? o.w : 0.01f * o.w;
        *(float4*)&ob[(size_t)(n0 + row) * ORS + d4] = o;
    }
}

// ---------------------------------------------------------------- K4: L2 fused masked attention
__global__ __launch_bounds__(256) void attn6w(const u16* __restrict__ hhi,
                                              const float* __restrict__ hf,
                                              const u32* __restrict__ adjx,
                                              const float* __restrict__ bias,
                                              float* __restrict__ outp) {
    constexpr int DK = 64, NC = 2, CMAX = 16;
    constexpr int QR = 128;
    constexpr int HBUF = QR * DK;
    const u32 NEGK = 0xFF800000u;

    int bx = blockIdx.x;
    int b = bx & 15, tile = bx >> 4;
    int n0 = tile * 64;
    const u16*   Hhi = hhi + (size_t)b * 1024 * DK;
    const float* Hf  = hf  + (size_t)b * 1024 * DK;
    float* ob = outp + (size_t)b * 1024 * 64;

    __shared__ __attribute__((aligned(16))) u16 Ksh[2 * HBUF];
    int   (*candm)[CMAX] = (int(*)[CMAX])Ksh;                // 4 KB @ 0
    float (*cands)[CMAX] = (float(*)[CMAX])(Ksh + 2048);     // 4 KB @ 4K
    int* cnt = (int*)(Ksh + 4096);                           // 256 B @ 8K
    int* wl  = (int*)(Ksh + 4224);                           // 4 KB @ 8.25K
    int* wln = (int*)(Ksh + 6272);                           // 4 B @ 12.25K

    int t = threadIdx.x, lane = t & 63, w = t >> 6;
    int l15 = lane & 15, q4 = lane >> 4;

    uint2 adm[4];
#pragma unroll
    for (int rg = 0; rg < 4; ++rg) {
        int row = w * 16 + q4 * 4 + rg;
        adm[rg] = *(const uint2*)&adjx[((size_t)(n0 + row) * 16 + l15) * 2];
    }

    short8 af[NC];
    {
        int ar = n0 + w * 16 + l15;
#pragma unroll
        for (int c = 0; c < NC; ++c)
            af[c] = *(const short8*)&Hhi[(size_t)ar * DK + c * 32 + q4 * 8];
    }

    u32 goff[4];
#pragma unroll
    for (int i = 0; i < 4; ++i) {
        int q = i * 64 + lane;
        int lr = w * 32 + (q >> 3);
        int sl = q & 7;
        goff[i] = (u32)(lr * DK + ((sl ^ (lr & 7)) << 3));
    }

    float t0[4], t1[4];
#pragma unroll
    for (int rg = 0; rg < 4; ++rg) { t0[rg] = __uint_as_float(NEGK); t1[rg] = __uint_as_float(NEGK); }

#pragma unroll
    for (int i = 0; i < 4; ++i)
        __builtin_amdgcn_global_load_lds(
            (const GLOBAL_AS u32*)(Hhi + goff[i]),
            (LDS_AS u32*)&Ksh[w * 32 * DK + i * 512], 16, 0, 0);

    for (int s = 0; s < 8; ++s) {
        __syncthreads();
        if (s < 7) {
            const u16* gp = Hhi + (size_t)(s + 1) * QR * DK;
            int obuf = (s + 1) & 1;
#pragma unroll
            for (int i = 0; i < 4; ++i)
                __builtin_amdgcn_global_load_lds(
                    (const GLOBAL_AS u32*)(gp + goff[i]),
                    (LDS_AS u32*)&Ksh[obuf * HBUF + w * 32 * DK + i * 512], 16, 0, 0);
        }
        const u16* Kb = Ksh + (s & 1) * HBUF;
#pragma unroll
        for (int mq = 0; mq < 2; ++mq) {
            int m0 = s * QR + mq * 64;
            int J0 = m0 >> 4, shb = J0 & 31;
            u32 wmsel[4];
#pragma unroll
            for (int rg = 0; rg < 4; ++rg) wmsel[rg] = (J0 & 32) ? adm[rg].y : adm[rg].x;
#pragma unroll
            for (int mt = 0; mt < 4; ++mt) {
                int mloc = mq * 64 + mt * 16 + l15;
                short8 bf[NC];
#pragma unroll
                for (int c = 0; c < NC; ++c) {
                    int slot = (c * 4 + q4) ^ (mloc & 7);
                    bf[c] = *(const short8*)&Kb[mloc * DK + slot * 8];
                }
                int jcol = m0 + mt * 16 + l15;
                f32x4 acc = {0.f, 0.f, 0.f, 0.f};
#pragma unroll
                for (int c = 0; c < NC; ++c)
                    acc = __builtin_amdgcn_mfma_f32_16x16x32_bf16(af[c], bf[c], acc, 0, 0, 0);
#pragma unroll
                for (int rg = 0; rg < 4; ++rg) {
                    u32 pk = (__float_as_uint(acc[rg]) & 0xFFFFFC00u) | (u32)jcol;
                    u32 msk = (u32)__builtin_amdgcn_sbfe((int)wmsel[rg], shb + mt, 1);
                    u32 pmu = (pk & msk) | (NEGK & ~msk);
                    float tf = __uint_as_float(pmu);
                    t1[rg] = __builtin_amdgcn_fmed3f(tf, t0[rg], t1[rg]);
                    t0[rg] = fmaxf(t0[rg], tf);
                }
            }
        }
    }
    __syncthreads();
    if (t < 64) cnt[t] = 0;
    if (t == 0) *wln = 0;
    __syncthreads();

#pragma unroll
    for (int rg = 0; rg < 4; ++rg) {
        float m = t0[rg];
#pragma unroll
        for (int off = 1; off < 16; off <<= 1) m = fmaxf(m, __shfl_xor(m, off));
        float thr = m - (100.0f + 0.04f * fabsf(m));
        int row = w * 16 + q4 * 4 + rg;
        if (t0[rg] > thr) {
            int p = atomicAdd(&cnt[row], 1);
            if (p < CMAX) candm[row][p] = (int)(__float_as_uint(t0[rg]) & 1023u);
        }
        if (t1[rg] > thr) {
            int p = atomicAdd(&cnt[row], 1);
            if (p < CMAX) candm[row][p] = (int)(__float_as_uint(t1[rg]) & 1023u);
        }
    }
    __syncthreads();

    // compact (row,ci) worklist
    if (t < 64) {
        int kc = cnt[t]; if (kc > CMAX) kc = CMAX;
        int base = atomicAdd(wln, kc);
        for (int i = 0; i < kc; ++i) wl[base + i] = (t << 4) | i;
    }
    __syncthreads();

    // exact fp32 dots: one 8-lane group per candidate
    {
        int M = *wln;
        int g = t >> 3, l = t & 7;
        for (int e = g; e < M; e += 32) {
            int pk = wl[e];
            int row = pk >> 4, ci = pk & 15;
            const float* qa = Hf + (size_t)(n0 + row) * DK + l * (DK / 8);
            const float* kb = Hf + (size_t)candm[row][ci] * DK + l * (DK / 8);
            float acc = 0.f;
#pragma unroll
            for (int d = 0; d < DK / 8; d += 4) {
                float4 a  = *(const float4*)&qa[d];
                float4 bv = *(const float4*)&kb[d];
                acc += a.x * bv.x + a.y * bv.y + a.z * bv.z + a.w * bv.w;
            }
            acc += __shfl_xor(acc, 4);
            acc += __shfl_xor(acc, 2);
            acc += __shfl_xor(acc, 1);
            if (l == 0) cands[row][ci] = acc;
        }
    }
    __syncthreads();

    if (t < 64) {
        int row = t;
        int kc = cnt[row]; if (kc > CMAX) kc = CMAX;
        float M = -3e38f;
        for (int i = 0; i < kc; ++i) M = fmaxf(M, cands[row][i]);
        float L = 0.f;
        for (int i = 0; i < kc; ++i) { float p = expf(cands[row][i] - M); cands[row][i] = p; L += p; }
        float inv = 1.f / L;
        for (int i = 0; i < kc; ++i) cands[row][i] *= inv;
    }
    __syncthreads();

    for (int e = t; e < 64 * 16; e += 256) {
        int row = e / 16, d4 = (e % 16) * 4;
        int kc = cnt[row]; if (kc > CMAX) kc = CMAX;
        float4 o = *(const float4*)&bias[d4];
        for (int i = 0; i < kc; ++i) {
            float p = cands[row][i];
            const float4 hv = *(const float4*)&Hf[(size_t)candm[row][i] * DK + d4];
            o.x += p * hv.x; o.y += p * hv.y; o.z += p * hv.z; o.w += p * hv.w;
        }
        o.x = o.x > 0.f ? o.x : 0.01f * o.x;
        o.y = o.y > 0.f ? o.y : 0.01f * o.y;
        o.z = o.z > 0.f ? o.z : 0.01f * o.z;
        o.w = o.w > 0.f ? o.w : 0.01f * o.w;
        *(float4*)&ob[(size_t)(n0 + row) * 64 + d4] = o;
    }
}

// ---------------------------------------------------------------- launcher
extern "C" void kernel_launch(void* const* d_in, const int* in_sizes, int n_in,
                              void* d_out, int out_size, void* d_ws, size_t ws_size,
                              hipStream_t stream) {
    (void)in_sizes; (void)n_in; (void)out_size; (void)ws_size;
    const float* flow_x = (const float*)d_in[0];   // [16,1024,64]
    const float* graph  = (const float*)d_in[1];   // [1024,1024]
    const float* Wh     = (const float*)d_in[2];   // [8,64,128]
    const float* bh     = (const float*)d_in[3];   // [8,128]
    const float* W_out  = (const float*)d_in[4];   // [1024,64]
    const float* b_out  = (const float*)d_in[5];   // [64]
    float* out = (float*)d_out;                    // [16,1024,64] fp32

    // workspace carve-up (~167 MB; all 16B-aligned)
    float* h_f32 = (float*)d_ws;                       // 16,777,216 f  [bh][n][128]
    float* x2    = h_f32 + 16777216;                   // 16,777,216 f  [b][n][1024]
    float* h2    = x2 + 16777216;                      //  1,048,576 f  [b][n][64]
    u16*  h_hi   = (u16*)(h2 + 1048576);               // 16,777,216 u16
    u16*  h2_hi  = h_hi + 16777216;                    //  1,048,576 u16
    u32*  adjx   = (u32*)(h2_hi + 1048576);            //     32,768 u32 (residue-bucketed)
    u16*  wfh    = (u16*)(adjx + 32768);               //     65,536 u16 (W_out hi frags)
    u16*  wfm    = wfh + 65536;                        //     65,536 u16 (W_out mid frags)
    u16*  wfl    = wfm + 65536;                        //     65,536 u16 (W_out lo frags)

    pack_adj3<<<1024, 256, 0, stream>>>(graph, adjx);
    wcvt<<<32, 256, 0, stream>>>(W_out, wfh, wfm, wfl);
    proj1<<<dim3(128, 8), 256, 0, stream>>>(flow_x, Wh, h_f32, h_hi);
    attn6<128, 8, 1024, 128><<<1024, 256, 0, stream>>>(h_hi, h_f32, adjx, bh, x2);
    proj2m<<<512, 256, 0, stream>>>(x2, wfh, wfm, wfl, h2, h2_hi);
    attn6w<<<256, 256, 0, stream>>>(h2_hi, h2, adjx, b_out, out);
}

// Round 6
// 244.716 us; speedup vs baseline: 1.1039x; 1.0002x over previous
//
#include <hip/hip_runtime.h>
#include <cstdint>
#include <cstddef>

// GATNet on MI355X — round 19 (= round 18 resubmitted; container infra
// failure gave no data, kernel unchanged for clean A/B).
// Base = round 17 (244.8us, absmax 2.0): proj2m 3-way bf16 MFMA GEMM for
// h2 (proj2p/reduce2 eliminated), attn6 = round-14 cooperative staging.
// attn6 main-loop change under test: replace __syncthreads (compiler
// drains vmcnt(0) every iter) with raw s_barrier pair + COUNTED vmcnt(4):
//   issue loads(t+1) -> vmcnt(4) [tile-t landed, t+1 in flight] ->
//   s_barrier [RAW] -> compute(buf) -> s_barrier [WAR].
// Cooperative staging kept (1x traffic). Prefetch spans barriers.

typedef short short8 __attribute__((ext_vector_type(8)));
typedef float f32x4  __attribute__((ext_vector_type(4)));
typedef unsigned short u16;
typedef unsigned char  u8;
typedef unsigned int   u32;

#define GLOBAL_AS __attribute__((address_space(1)))
#define LDS_AS    __attribute__((address_space(3)))

__device__ __forceinline__ u16 f2bf(float f) {        // RNE float->bf16 bits
    u32 x = __float_as_uint(f);
    u32 r = (x + 0x7FFFu + ((x >> 16) & 1u)) >> 16;
    return (u16)r;
}

// ---------------------------------------------------------------- K0: graph -> residue-bucketed bitmasks
__global__ __launch_bounds__(256) void pack_adj3(const float* __restrict__ g,
                                                 u32* __restrict__ adjx) {
    int n = blockIdx.x, t = threadIdx.x;
    __shared__ u8 bits[1024];
    float4 v = *(const float4*)&g[(size_t)n * 1024 + t * 4];
    bits[t * 4 + 0] = v.x != 0.0f;
    bits[t * 4 + 1] = v.y != 0.0f;
    bits[t * 4 + 2] = v.z != 0.0f;
    bits[t * 4 + 3] = v.w != 0.0f;
    __syncthreads();
    if (t < 32) {
        int r = t >> 1, h = t & 1;
        u32 wd = 0;
#pragma unroll
        for (int j = 0; j < 32; ++j)
            wd |= (u32)bits[16 * (h * 32 + j) + r] << j;
        adjx[((size_t)n * 16 + r) * 2 + h] = wd;
    }
}

// ---------------------------------------------------------------- K1: h = x @ Wh  (fp32 exact + bf16-hi copy)
__global__ __launch_bounds__(256) void proj1(const float* __restrict__ x,
                                             const float* __restrict__ Whg,
                                             float* __restrict__ hf,
                                             u16* __restrict__ hhi) {
    int bh = blockIdx.x;                 // b*8+hd
    int hd = bh & 7, bb = bh >> 3;
    int n0 = blockIdx.y * 128;
    const float* W  = Whg + (size_t)hd * 64 * 128;
    const float* xb = x + ((size_t)bb * 1024 + n0) * 64;
    __shared__ __attribute__((aligned(16))) float ws[32][132];
    __shared__ __attribute__((aligned(16))) float xsT[32][132];
    int t = threadIdx.x;
    int rg = t >> 4, cg = t & 15;
    int r0 = rg * 8, c0 = cg * 8;
    float acc[8][8] = {};
    for (int kt = 0; kt < 2; ++kt) {
        int kb = kt * 32;
        for (int u = t; u < 1024; u += 256) {
            int k = u >> 5, d4 = (u & 31) << 2;
            *(float4*)&ws[k][d4] = *(const float4*)&W[(size_t)(kb + k) * 128 + d4];
        }
        for (int u = t; u < 1024; u += 256) {
            int r = u >> 3, k4 = (u & 7) << 2;
            float4 xv = *(const float4*)&xb[(size_t)r * 64 + kb + k4];
            xsT[k4 + 0][r] = xv.x; xsT[k4 + 1][r] = xv.y;
            xsT[k4 + 2][r] = xv.z; xsT[k4 + 3][r] = xv.w;
        }
        __syncthreads();
        for (int k = 0; k < 32; ++k) {
            float4 xa = *(float4*)&xsT[k][r0];
            float4 xbv = *(float4*)&xsT[k][r0 + 4];
            float4 wa = *(float4*)&ws[k][c0];
            float4 wb = *(float4*)&ws[k][c0 + 4];
            float xq[8] = {xa.x, xa.y, xa.z, xa.w, xbv.x, xbv.y, xbv.z, xbv.w};
            float wv[8] = {wa.x, wa.y, wa.z, wa.w, wb.x, wb.y, wb.z, wb.w};
#pragma unroll
            for (int i = 0; i < 8; ++i)
#pragma unroll
                for (int j = 0; j < 8; ++j)
                    acc[i][j] = fmaf(xq[i], wv[j], acc[i][j]);
        }
        __syncthreads();
    }
#pragma unroll
    for (int i = 0; i < 8; ++i) {
        int n = n0 + r0 + i;
        size_t base = ((size_t)bh * 1024 + n) * 128 + c0;
        float4 f0 = {acc[i][0], acc[i][1], acc[i][2], acc[i][3]};
        float4 f1 = {acc[i][4], acc[i][5], acc[i][6], acc[i][7]};
        *(float4*)&hf[base]     = f0;
        *(float4*)&hf[base + 4] = f1;
        uint4 up;
        up.x = (u32)f2bf(acc[i][0]) | ((u32)f2bf(acc[i][1]) << 16);
        up.y = (u32)f2bf(acc[i][2]) | ((u32)f2bf(acc[i][3]) << 16);
        up.z = (u32)f2bf(acc[i][4]) | ((u32)f2bf(acc[i][5]) << 16);
        up.w = (u32)f2bf(acc[i][6]) | ((u32)f2bf(acc[i][7]) << 16);
        *(uint4*)&hhi[base] = up;
    }
}

// ---------------------------------------------------------------- K3a: W_out -> MFMA-fragment-ordered bf16 h/m/l
__global__ __launch_bounds__(256) void wcvt(const float* __restrict__ Wo,
                                            u16* __restrict__ wfh,
                                            u16* __restrict__ wfm,
                                            u16* __restrict__ wfl) {
    int g = blockIdx.x * 256 + threadIdx.x;      // 8192 groups, 32 blocks
    int lane = g & 63, s = (g >> 6) & 31, c = g >> 11;
    int col = c * 16 + (lane & 15);
    int k0 = s * 32 + (lane >> 4) * 8;
    u32 hp[4], mp[4], lp[4];
#pragma unroll
    for (int jj = 0; jj < 4; ++jj) {
        float x0 = Wo[(size_t)(k0 + jj * 2 + 0) * 64 + col];
        float x1 = Wo[(size_t)(k0 + jj * 2 + 1) * 64 + col];
        u16 h0 = f2bf(x0), h1 = f2bf(x1);
        float r0 = x0 - __uint_as_float((u32)h0 << 16);
        float r1 = x1 - __uint_as_float((u32)h1 << 16);
        u16 m0 = f2bf(r0), m1 = f2bf(r1);
        float s0 = r0 - __uint_as_float((u32)m0 << 16);
        float s1 = r1 - __uint_as_float((u32)m1 << 16);
        u16 l0 = f2bf(s0), l1 = f2bf(s1);
        hp[jj] = (u32)h0 | ((u32)h1 << 16);
        mp[jj] = (u32)m0 | ((u32)m1 << 16);
        lp[jj] = (u32)l0 | ((u32)l1 << 16);
    }
    uint4 hv = {hp[0], hp[1], hp[2], hp[3]};
    uint4 mv = {mp[0], mp[1], mp[2], mp[3]};
    uint4 lv = {lp[0], lp[1], lp[2], lp[3]};
    *(uint4*)&wfh[(size_t)g * 8] = hv;
    *(uint4*)&wfm[(size_t)g * 8] = mv;
    *(uint4*)&wfl[(size_t)g * 8] = lv;
}

// ---------------------------------------------------------------- K3b: h2 = x2 @ W_out via 3-way bf16 MFMA
__global__ __launch_bounds__(256) void proj2m(const float* __restrict__ x2,
                                              const u16* __restrict__ wfh,
                                              const u16* __restrict__ wfm,
                                              const u16* __restrict__ wfl,
                                              float* __restrict__ h2f,
                                              u16* __restrict__ h2hi) {
    int bx = blockIdx.x;
    int b = bx & 15, tile = bx >> 4;
    int n0 = tile * 32;
    const float* X = x2 + ((size_t)b * 1024 + n0) * 1024;

    __shared__ __attribute__((aligned(16))) u16 Ah[2][32][40];   // +8 pad
    __shared__ __attribute__((aligned(16))) u16 Am[2][32][40];
    __shared__ __attribute__((aligned(16))) u16 Al[2][32][40];

    int t = threadIdx.x, lane = t & 63, w = t >> 6;
    int l15 = lane & 15, q4 = lane >> 4;
    int rf = w & 1, cs = w >> 1;
    int rstage = t >> 3, kseg = t & 7;

    f32x4 acc0 = {0.f, 0.f, 0.f, 0.f}, acc1 = {0.f, 0.f, 0.f, 0.f};

    auto stage = [&](int buf, const float4& xv) {
        float xs[4] = {xv.x, xv.y, xv.z, xv.w};
        u16 hh[4], mm_[4], ll[4];
#pragma unroll
        for (int j = 0; j < 4; ++j) {
            u16 h = f2bf(xs[j]);
            float r1 = xs[j] - __uint_as_float((u32)h << 16);
            u16 m = f2bf(r1);
            float r2 = r1 - __uint_as_float((u32)m << 16);
            u16 l = f2bf(r2);
            hh[j] = h; mm_[j] = m; ll[j] = l;
        }
        uint2 hp = {(u32)hh[0] | ((u32)hh[1] << 16), (u32)hh[2] | ((u32)hh[3] << 16)};
        uint2 mp = {(u32)mm_[0] | ((u32)mm_[1] << 16), (u32)mm_[2] | ((u32)mm_[3] << 16)};
        uint2 lp = {(u32)ll[0] | ((u32)ll[1] << 16), (u32)ll[2] | ((u32)ll[3] << 16)};
        *(uint2*)&Ah[buf][rstage][kseg * 4] = hp;
        *(uint2*)&Am[buf][rstage][kseg * 4] = mp;
        *(uint2*)&Al[buf][rstage][kseg * 4] = lp;
    };

    float4 xv0 = *(const float4*)&X[(size_t)rstage * 1024 + kseg * 4];
    stage(0, xv0);
    float4 xva = *(const float4*)&X[(size_t)rstage * 1024 + 32 + kseg * 4];
    float4 xvb = *(const float4*)&X[(size_t)rstage * 1024 + 64 + kseg * 4];

    for (int s = 0; s < 32; ++s) {
        __syncthreads();                   // tile s staged & visible
        int buf = s & 1;
        if (s < 31) {
            stage(buf ^ 1, xva);           // stage tile s+1
            xva = xvb;
            if (s < 30)
                xvb = *(const float4*)&X[(size_t)rstage * 1024 + (s + 3) * 32 + kseg * 4];
        }
        short8 ah = *(const short8*)&Ah[buf][rf * 16 + l15][q4 * 8];
        short8 am = *(const short8*)&Am[buf][rf * 16 + l15][q4 * 8];
        short8 al = *(const short8*)&Al[buf][rf * 16 + l15][q4 * 8];
        size_t f0 = ((size_t)((cs * 2 + 0) * 32 + s) * 64 + lane) * 8;
        size_t f1 = ((size_t)((cs * 2 + 1) * 32 + s) * 64 + lane) * 8;
        short8 bh0 = *(const short8*)&wfh[f0];
        short8 bm0 = *(const short8*)&wfm[f0];
        short8 bl0 = *(const short8*)&wfl[f0];
        short8 bh1 = *(const short8*)&wfh[f1];
        short8 bm1 = *(const short8*)&wfm[f1];
        short8 bl1 = *(const short8*)&wfl[f1];
        acc0 = __builtin_amdgcn_mfma_f32_16x16x32_bf16(ah, bh0, acc0, 0, 0, 0);
        acc0 = __builtin_amdgcn_mfma_f32_16x16x32_bf16(ah, bm0, acc0, 0, 0, 0);
        acc0 = __builtin_amdgcn_mfma_f32_16x16x32_bf16(am, bh0, acc0, 0, 0, 0);
        acc0 = __builtin_amdgcn_mfma_f32_16x16x32_bf16(ah, bl0, acc0, 0, 0, 0);
        acc0 = __builtin_amdgcn_mfma_f32_16x16x32_bf16(am, bm0, acc0, 0, 0, 0);
        acc0 = __builtin_amdgcn_mfma_f32_16x16x32_bf16(al, bh0, acc0, 0, 0, 0);
        acc1 = __builtin_amdgcn_mfma_f32_16x16x32_bf16(ah, bh1, acc1, 0, 0, 0);
        acc1 = __builtin_amdgcn_mfma_f32_16x16x32_bf16(ah, bm1, acc1, 0, 0, 0);
        acc1 = __builtin_amdgcn_mfma_f32_16x16x32_bf16(am, bh1, acc1, 0, 0, 0);
        acc1 = __builtin_amdgcn_mfma_f32_16x16x32_bf16(ah, bl1, acc1, 0, 0, 0);
        acc1 = __builtin_amdgcn_mfma_f32_16x16x32_bf16(am, bm1, acc1, 0, 0, 0);
        acc1 = __builtin_amdgcn_mfma_f32_16x16x32_bf16(al, bh1, acc1, 0, 0, 0);
    }

    // C frag: col = lane&15, row = q4*4 + i
#pragma unroll
    for (int i = 0; i < 4; ++i) {
        int row = n0 + rf * 16 + q4 * 4 + i;
        size_t a0 = ((size_t)b * 1024 + row) * 64 + (cs * 2 + 0) * 16 + l15;
        size_t a1 = ((size_t)b * 1024 + row) * 64 + (cs * 2 + 1) * 16 + l15;
        h2f[a0] = acc0[i];  h2hi[a0] = f2bf(acc0[i]);
        h2f[a1] = acc1[i];  h2hi[a1] = f2bf(acc1[i]);
    }
}

// ---------------------------------------------------------------- K2: L1 fused masked attention
// Cooperative double-buffered staging; raw-barrier main loop with COUNTED
// vmcnt (prefetch spans barriers, no drain). 32768 B LDS, aliased epilogue.
template <int DK, int NH, int ORS, int RT>
__global__ __launch_bounds__(256, 4) void attn6(const u16* __restrict__ hhi,
                                                const float* __restrict__ hf,
                                                const u32* __restrict__ adjx,
                                                const float* __restrict__ bias,
                                                float* __restrict__ outp) {
    constexpr int CR   = DK / 8;
    constexpr int NC   = DK / 32;
    constexpr int LGCR = (CR == 16) ? 4 : 3;
    constexpr int RPI  = 64 / CR;
    constexpr int NI   = 16 / RPI;
    constexpr int RW   = RT / 4;
    constexpr int RS   = RW / 16;
    constexpr int NBH  = NH * 16;
    constexpr int CMAX = 16;
    constexpr int HBUF = 64 * DK;         // u16 per staging buffer
    const u32 NEGK = 0xFF800000u;

    int bx = blockIdx.x;
    int bh = bx % NBH, tile = bx / NBH;   // XCD swizzle: bx%8 == bh%8
    int hd = (NH == 1) ? 0 : (bh & (NH - 1));
    int b  = (NH == 1) ? bh : (bh >> 3);
    int n0 = tile * RT;
    const u16*   Hhi = hhi + (size_t)bh * 1024 * DK;
    const float* Hf  = hf  + (size_t)bh * 1024 * DK;
    const float* bs  = bias + (size_t)hd * DK;
    float* ob = outp + (size_t)b * 1024 * ORS + (size_t)hd * DK;

    __shared__ __attribute__((aligned(16))) char smem[2 * HBUF * 2];   // 32768 B
    u16* Ksh = (u16*)smem;
    int   (*candm)[CMAX] = (int(*)[CMAX])smem;               // 8 KB @ 0
    float (*cands)[CMAX] = (float(*)[CMAX])(smem + 8192);    // 8 KB @ 8K
    int*   cnt           = (int*)(smem + 16384);             // 512 B @ 16K
    int*   wl            = (int*)(smem + 16896);             // 8 KB @ 16.5K
    int*   wln           = (int*)(smem + 25088);             // 4 B

    int t = threadIdx.x, lane = t & 63, w = t >> 6;
    int l15 = lane & 15, q4 = lane >> 4;

    uint2 adm[RS][4];
#pragma unroll
    for (int rs = 0; rs < RS; ++rs)
#pragma unroll
        for (int rg = 0; rg < 4; ++rg) {
            int row = w * RW + rs * 16 + q4 * 4 + rg;
            adm[rs][rg] = *(const uint2*)&adjx[((size_t)(n0 + row) * 16 + l15) * 2];
        }

    short8 af[RS][NC];
#pragma unroll
    for (int rs = 0; rs < RS; ++rs) {
        int ar = n0 + w * RW + rs * 16 + l15;
#pragma unroll
        for (int c = 0; c < NC; ++c)
            af[rs][c] = *(const short8*)&Hhi[(size_t)ar * DK + c * 32 + q4 * 8];
    }

    int mb = w * 16 + (lane >> LGCR);
    int sl = lane & (CR - 1);
    u32 goff[NI];
#pragma unroll
    for (int i = 0; i < NI; ++i) {
        int m = mb + i * RPI;
        goff[i] = (u32)(m * DK + ((sl ^ (m & (CR - 1))) << 3));
    }

    float t0[RS][4], t1[RS][4];
#pragma unroll
    for (int rs = 0; rs < RS; ++rs)
#pragma unroll
        for (int rg = 0; rg < 4; ++rg) {
            t0[rs][rg] = __uint_as_float(NEGK);
            t1[rs][rg] = __uint_as_float(NEGK);
        }

    {
        const u16* gp = Hhi;
#pragma unroll
        for (int i = 0; i < NI; ++i)
            __builtin_amdgcn_global_load_lds(
                (const GLOBAL_AS u32*)(gp + goff[i]),
                (LDS_AS u32*)&Ksh[w * 16 * DK + i * 512], 16, 0, 0);
    }
    for (int m0 = 0; m0 < 1024; m0 += 64) {
        int buf = (m0 >> 6) & 1;
        // issue prefetch of tile t+1, then COUNTED wait: tile t landed, t+1
        // stays in flight across both barriers.
        if (m0 + 64 < 1024) {
            const u16* gp = Hhi + (size_t)(m0 + 64) * DK;
#pragma unroll
            for (int i = 0; i < NI; ++i)
                __builtin_amdgcn_global_load_lds(
                    (const GLOBAL_AS u32*)(gp + goff[i]),
                    (LDS_AS u32*)&Ksh[(buf ^ 1) * HBUF + w * 16 * DK + i * 512], 16, 0, 0);
            asm volatile("s_waitcnt vmcnt(4)" ::: "memory");
        } else {
            asm volatile("s_waitcnt vmcnt(0)" ::: "memory");
        }
        __builtin_amdgcn_sched_barrier(0);
        asm volatile("s_barrier" ::: "memory");       // RAW: everyone's tile t landed

        const u16* Kb = Ksh + buf * HBUF;
        int J0 = m0 >> 4, shb = J0 & 31;
        u32 wmsel[RS][4];
#pragma unroll
        for (int rs = 0; rs < RS; ++rs)
#pragma unroll
            for (int rg = 0; rg < 4; ++rg)
                wmsel[rs][rg] = (J0 & 32) ? adm[rs][rg].y : adm[rs][rg].x;
#pragma unroll
        for (int mt = 0; mt < 4; ++mt) {
            int mrow = mt * 16 + l15;
            short8 bf[NC];
#pragma unroll
            for (int c = 0; c < NC; ++c) {
                int slot = (c * 4 + q4) ^ (mrow & (CR - 1));
                bf[c] = *(const short8*)&Kb[mrow * DK + slot * 8];
            }
            int jcol = m0 + mt * 16 + l15;
#pragma unroll
            for (int rs = 0; rs < RS; ++rs) {
                f32x4 acc = {0.f, 0.f, 0.f, 0.f};
#pragma unroll
                for (int c = 0; c < NC; ++c)
                    acc = __builtin_amdgcn_mfma_f32_16x16x32_bf16(af[rs][c], bf[c], acc, 0, 0, 0);
#pragma unroll
                for (int rg = 0; rg < 4; ++rg) {
                    u32 pk = (__float_as_uint(acc[rg]) & 0xFFFFFC00u) | (u32)jcol; // v_and_or
                    u32 msk = (u32)__builtin_amdgcn_sbfe((int)wmsel[rs][rg], shb + mt, 1);
                    u32 pmu = (pk & msk) | (NEGK & ~msk);                          // v_bfi
                    float tf = __uint_as_float(pmu);
                    t1[rs][rg] = __builtin_amdgcn_fmed3f(tf, t0[rs][rg], t1[rs][rg]);
                    t0[rs][rg] = fmaxf(t0[rs][rg], tf);
                }
            }
        }
        asm volatile("s_barrier" ::: "memory");       // WAR: all waves done with buf
    }
    __syncthreads();                       // all staging dead; aliases usable
    for (int u = t; u < RT; u += 256) cnt[u] = 0;
    if (t == 0) *wln = 0;
    __syncthreads();

#pragma unroll
    for (int rs = 0; rs < RS; ++rs)
#pragma unroll
        for (int rg = 0; rg < 4; ++rg) {
            float m = t0[rs][rg];
#pragma unroll
            for (int off = 1; off < 16; off <<= 1) m = fmaxf(m, __shfl_xor(m, off));
            float thr = m - (100.0f + 0.04f * fabsf(m));
            int row = w * RW + rs * 16 + q4 * 4 + rg;
            if (t0[rs][rg] > thr) {
                int p = atomicAdd(&cnt[row], 1);
                if (p < CMAX) candm[row][p] = (int)(__float_as_uint(t0[rs][rg]) & 1023u);
            }
            if (t1[rs][rg] > thr) {
                int p = atomicAdd(&cnt[row], 1);
                if (p < CMAX) candm[row][p] = (int)(__float_as_uint(t1[rs][rg]) & 1023u);
            }
        }
    __syncthreads();

    // compact (row,ci) worklist
    if (t < RT) {
        int kc = cnt[t]; if (kc > CMAX) kc = CMAX;
        int base = atomicAdd(wln, kc);
        for (int i = 0; i < kc; ++i) wl[base + i] = (t << 4) | i;
    }
    __syncthreads();

    // exact fp32 dots: one 8-lane group per candidate, coalesced 128B segments
    {
        int M = *wln;
        int g = t >> 3, l = t & 7;
        for (int e = g; e < M; e += 32) {
            int pk = wl[e];
            int row = pk >> 4, ci = pk & 15;
            const float* qa = Hf + (size_t)(n0 + row) * DK + l * (DK / 8);
            const float* kb = Hf + (size_t)candm[row][ci] * DK + l * (DK / 8);
            float acc = 0.f;
#pragma unroll
            for (int d = 0; d < DK / 8; d += 4) {
                float4 a  = *(const float4*)&qa[d];
                float4 bv = *(const float4*)&kb[d];
                acc += a.x * bv.x + a.y * bv.y + a.z * bv.z + a.w * bv.w;
            }
            acc += __shfl_xor(acc, 4);
            acc += __shfl_xor(acc, 2);
            acc += __shfl_xor(acc, 1);
            if (l == 0) cands[row][ci] = acc;
        }
    }
    __syncthreads();

    for (int row = t; row < RT; row += 256) {
        int kc = cnt[row]; if (kc > CMAX) kc = CMAX;
        float M = -3e38f;
        for (int i = 0; i < kc; ++i) M = fmaxf(M, cands[row][i]);
        float L = 0.f;
        for (int i = 0; i < kc; ++i) { float p = expf(cands[row][i] - M); cands[row][i] = p; L += p; }
        float inv = 1.f / L;
        for (int i = 0; i < kc; ++i) cands[row][i] *= inv;
    }
    __syncthreads();

    constexpr int D4 = DK / 4;
    for (int e = t; e < RT * D4; e += 256) {
        int row = e / D4, d4 = (e % D4) * 4;
        int kc = cnt[row]; if (kc > CMAX) kc = CMAX;
        float4 o = *(const float4*)&bs[d4];
        for (int i = 0; i < kc; ++i) {
            float p = cands[row][i];
            const float4 hv = *(const float4*)&Hf[(size_t)candm[row][i] * DK + d4];
            o.x += p * hv.x; o.y += p * hv.y; o.z += p * hv.z; o.w += p * hv.w;
        }
        o.x = o.x > 0.f ? o.x : 0.01f * o.x;
        o.y = o.y > 0.f ? o.y : 0.01f * o.y;
        o.z = o.z > 0.f ? o.z : 0.01f * o.z;
        o.w = o.w > 0.f ? o.w : 0.01f * o.w;
        *(float4*)&ob[(size_t)(n0 + row) * ORS + d4] = o;
    }
}

// ---------------------------------------------------------------- K4: L2 fused masked attention
__global__ __launch_bounds__(256) void attn6w(const u16* __restrict__ hhi,
                                              const float* __restrict__ hf,
                                              const u32* __restrict__ adjx,
                                              const float* __restrict__ bias,
                                              float* __restrict__ outp) {
    constexpr int DK = 64, NC = 2, CMAX = 16;
    constexpr int QR = 128;
    constexpr int HBUF = QR * DK;
    const u32 NEGK = 0xFF800000u;

    int bx = blockIdx.x;
    int b = bx & 15, tile = bx >> 4;
    int n0 = tile * 64;
    const u16*   Hhi = hhi + (size_t)b * 1024 * DK;
    const float* Hf  = hf  + (size_t)b * 1024 * DK;
    float* ob = outp + (size_t)b * 1024 * 64;

    __shared__ __attribute__((aligned(16))) u16 Ksh[2 * HBUF];
    int   (*candm)[CMAX] = (int(*)[CMAX])Ksh;                // 4 KB @ 0
    float (*cands)[CMAX] = (float(*)[CMAX])(Ksh + 2048);     // 4 KB @ 4K
    int* cnt = (int*)(Ksh + 4096);                           // 256 B @ 8K
    int* wl  = (int*)(Ksh + 4224);                           // 4 KB @ 8.25K
    int* wln = (int*)(Ksh + 6272);                           // 4 B @ 12.25K

    int t = threadIdx.x, lane = t & 63, w = t >> 6;
    int l15 = lane & 15, q4 = lane >> 4;

    uint2 adm[4];
#pragma unroll
    for (int rg = 0; rg < 4; ++rg) {
        int row = w * 16 + q4 * 4 + rg;
        adm[rg] = *(const uint2*)&adjx[((size_t)(n0 + row) * 16 + l15) * 2];
    }

    short8 af[NC];
    {
        int ar = n0 + w * 16 + l15;
#pragma unroll
        for (int c = 0; c < NC; ++c)
            af[c] = *(const short8*)&Hhi[(size_t)ar * DK + c * 32 + q4 * 8];
    }

    u32 goff[4];
#pragma unroll
    for (int i = 0; i < 4; ++i) {
        int q = i * 64 + lane;
        int lr = w * 32 + (q >> 3);
        int sl = q & 7;
        goff[i] = (u32)(lr * DK + ((sl ^ (lr & 7)) << 3));
    }

    float t0[4], t1[4];
#pragma unroll
    for (int rg = 0; rg < 4; ++rg) { t0[rg] = __uint_as_float(NEGK); t1[rg] = __uint_as_float(NEGK); }

#pragma unroll
    for (int i = 0; i < 4; ++i)
        __builtin_amdgcn_global_load_lds(
            (const GLOBAL_AS u32*)(Hhi + goff[i]),
            (LDS_AS u32*)&Ksh[w * 32 * DK + i * 512], 16, 0, 0);

    for (int s = 0; s < 8; ++s) {
        __syncthreads();
        if (s < 7) {
            const u16* gp = Hhi + (size_t)(s + 1) * QR * DK;
            int obuf = (s + 1) & 1;
#pragma unroll
            for (int i = 0; i < 4; ++i)
                __builtin_amdgcn_global_load_lds(
                    (const GLOBAL_AS u32*)(gp + goff[i]),
                    (LDS_AS u32*)&Ksh[obuf * HBUF + w * 32 * DK + i * 512], 16, 0, 0);
        }
        const u16* Kb = Ksh + (s & 1) * HBUF;
#pragma unroll
        for (int mq = 0; mq < 2; ++mq) {
            int m0 = s * QR + mq * 64;
            int J0 = m0 >> 4, shb = J0 & 31;
            u32 wmsel[4];
#pragma unroll
            for (int rg = 0; rg < 4; ++rg) wmsel[rg] = (J0 & 32) ? adm[rg].y : adm[rg].x;
#pragma unroll
            for (int mt = 0; mt < 4; ++mt) {
                int mloc = mq * 64 + mt * 16 + l15;
                short8 bf[NC];
#pragma unroll
                for (int c = 0; c < NC; ++c) {
                    int slot = (c * 4 + q4) ^ (mloc & 7);
                    bf[c] = *(const short8*)&Kb[mloc * DK + slot * 8];
                }
                int jcol = m0 + mt * 16 + l15;
                f32x4 acc = {0.f, 0.f, 0.f, 0.f};
#pragma unroll
                for (int c = 0; c < NC; ++c)
                    acc = __builtin_amdgcn_mfma_f32_16x16x32_bf16(af[c], bf[c], acc, 0, 0, 0);
#pragma unroll
                for (int rg = 0; rg < 4; ++rg) {
                    u32 pk = (__float_as_uint(acc[rg]) & 0xFFFFFC00u) | (u32)jcol;
                    u32 msk = (u32)__builtin_amdgcn_sbfe((int)wmsel[rg], shb + mt, 1);
                    u32 pmu = (pk & msk) | (NEGK & ~msk);
                    float tf = __uint_as_float(pmu);
                    t1[rg] = __builtin_amdgcn_fmed3f(tf, t0[rg], t1[rg]);
                    t0[rg] = fmaxf(t0[rg], tf);
                }
            }
        }
    }
    __syncthreads();
    if (t < 64) cnt[t] = 0;
    if (t == 0) *wln = 0;
    __syncthreads();

#pragma unroll
    for (int rg = 0; rg < 4; ++rg) {
        float m = t0[rg];
#pragma unroll
        for (int off = 1; off < 16; off <<= 1) m = fmaxf(m, __shfl_xor(m, off));
        float thr = m - (100.0f + 0.04f * fabsf(m));
        int row = w * 16 + q4 * 4 + rg;
        if (t0[rg] > thr) {
            int p = atomicAdd(&cnt[row], 1);
            if (p < CMAX) candm[row][p] = (int)(__float_as_uint(t0[rg]) & 1023u);
        }
        if (t1[rg] > thr) {
            int p = atomicAdd(&cnt[row], 1);
            if (p < CMAX) candm[row][p] = (int)(__float_as_uint(t1[rg]) & 1023u);
        }
    }
    __syncthreads();

    // compact (row,ci) worklist
    if (t < 64) {
        int kc = cnt[t]; if (kc > CMAX) kc = CMAX;
        int base = atomicAdd(wln, kc);
        for (int i = 0; i < kc; ++i) wl[base + i] = (t << 4) | i;
    }
    __syncthreads();

    // exact fp32 dots: one 8-lane group per candidate
    {
        int M = *wln;
        int g = t >> 3, l = t & 7;
        for (int e = g; e < M; e += 32) {
            int pk = wl[e];
            int row = pk >> 4, ci = pk & 15;
            const float* qa = Hf + (size_t)(n0 + row) * DK + l * (DK / 8);
            const float* kb = Hf + (size_t)candm[row][ci] * DK + l * (DK / 8);
            float acc = 0.f;
#pragma unroll
            for (int d = 0; d < DK / 8; d += 4) {
                float4 a  = *(const float4*)&qa[d];
                float4 bv = *(const float4*)&kb[d];
                acc += a.x * bv.x + a.y * bv.y + a.z * bv.z + a.w * bv.w;
            }
            acc += __shfl_xor(acc, 4);
            acc += __shfl_xor(acc, 2);
            acc += __shfl_xor(acc, 1);
            if (l == 0) cands[row][ci] = acc;
        }
    }
    __syncthreads();

    if (t < 64) {
        int row = t;
        int kc = cnt[row]; if (kc > CMAX) kc = CMAX;
        float M = -3e38f;
        for (int i = 0; i < kc; ++i) M = fmaxf(M, cands[row][i]);
        float L = 0.f;
        for (int i = 0; i < kc; ++i) { float p = expf(cands[row][i] - M); cands[row][i] = p; L += p; }
        float inv = 1.f / L;
        for (int i = 0; i < kc; ++i) cands[row][i] *= inv;
    }
    __syncthreads();

    for (int e = t; e < 64 * 16; e += 256) {
        int row = e / 16, d4 = (e % 16) * 4;
        int kc = cnt[row]; if (kc > CMAX) kc = CMAX;
        float4 o = *(const float4*)&bias[d4];
        for (int i = 0; i < kc; ++i) {
            float p = cands[row][i];
            const float4 hv = *(const float4*)&Hf[(size_t)candm[row][i] * DK + d4];
            o.x += p * hv.x; o.y += p * hv.y; o.z += p * hv.z; o.w += p * hv.w;
        }
        o.x = o.x > 0.f ? o.x : 0.01f * o.x;
        o.y = o.y > 0.f ? o.y : 0.01f * o.y;
        o.z = o.z > 0.f ? o.z : 0.01f * o.z;
        o.w = o.w > 0.f ? o.w : 0.01f * o.w;
        *(float4*)&ob[(size_t)(n0 + row) * 64 + d4] = o;
    }
}

// ---------------------------------------------------------------- launcher
extern "C" void kernel_launch(void* const* d_in, const int* in_sizes, int n_in,
                              void* d_out, int out_size, void* d_ws, size_t ws_size,
                              hipStream_t stream) {
    (void)in_sizes; (void)n_in; (void)out_size; (void)ws_size;
    const float* flow_x = (const float*)d_in[0];   // [16,1024,64]
    const float* graph  = (const float*)d_in[1];   // [1024,1024]
    const float* Wh     = (const float*)d_in[2];   // [8,64,128]
    const float* bh     = (const float*)d_in[3];   // [8,128]
    const float* W_out  = (const float*)d_in[4];   // [1024,64]
    const float* b_out  = (const float*)d_in[5];   // [64]
    float* out = (float*)d_out;                    // [16,1024,64] fp32

    // workspace carve-up (~167 MB; all 16B-aligned)
    float* h_f32 = (float*)d_ws;                       // 16,777,216 f  [bh][n][128]
    float* x2    = h_f32 + 16777216;                   // 16,777,216 f  [b][n][1024]
    float* h2    = x2 + 16777216;                      //  1,048,576 f  [b][n][64]
    u16*  h_hi   = (u16*)(h2 + 1048576);               // 16,777,216 u16
    u16*  h2_hi  = h_hi + 16777216;                    //  1,048,576 u16
    u32*  adjx   = (u32*)(h2_hi + 1048576);            //     32,768 u32 (residue-bucketed)
    u16*  wfh    = (u16*)(adjx + 32768);               //     65,536 u16 (W_out hi frags)
    u16*  wfm    = wfh + 65536;                        //     65,536 u16 (W_out mid frags)
    u16*  wfl    = wfm + 65536;                        //     65,536 u16 (W_out lo frags)

    pack_adj3<<<1024, 256, 0, stream>>>(graph, adjx);
    wcvt<<<32, 256, 0, stream>>>(W_out, wfh, wfm, wfl);
    proj1<<<dim3(128, 8), 256, 0, stream>>>(flow_x, Wh, h_f32, h_hi);
    attn6<128, 8, 1024, 128><<<1024, 256, 0, stream>>>(h_hi, h_f32, adjx, bh, x2);
    proj2m<<<512, 256, 0, stream>>>(x2, wfh, wfm, wfl, h2, h2_hi);
    attn6w<<<256, 256, 0, stream>>>(h2_hi, h2, adjx, b_out, out);
}

// Round 7
// 234.275 us; speedup vs baseline: 1.1531x; 1.0446x over previous
//
#include <hip/hip_runtime.h>
#include <cstdint>
#include <cstddef>

// GATNet on MI355X — round 20.
// attn6 = round-19 (counted vmcnt + raw barriers; measured == round-14's
// 94.6us — kept as control, unchanged). proj2m/attn6w unchanged.
// Round-20 change: proj1 (fp32 VALU GEMM, ~14us FMA floor + LDS transpose)
// replaced by proj1m: 3-way bf16 MFMA split (R17-proven recipe), K=64 = 2
// MFMA K-steps x 6 products. No LDS, no barriers, in-register A conversion,
// Wh pre-converted to fragment order. proj1m should land at the 96MB
// HBM-write floor (~16us). pack_adj3+wcvt+whcvt merged into one prep launch
// (6 -> 5 kernels).

typedef short short8 __attribute__((ext_vector_type(8)));
typedef float f32x4  __attribute__((ext_vector_type(4)));
typedef unsigned short u16;
typedef unsigned char  u8;
typedef unsigned int   u32;

#define GLOBAL_AS __attribute__((address_space(1)))
#define LDS_AS    __attribute__((address_space(3)))

__device__ __forceinline__ u16 f2bf(float f) {        // RNE float->bf16 bits
    u32 x = __float_as_uint(f);
    u32 r = (x + 0x7FFFu + ((x >> 16) & 1u)) >> 16;
    return (u16)r;
}

// ---------------------------------------------------------------- K0: prep
// bx<1024: graph->bitmasks; 1024..1055: W_out->3-way frags; 1056..1087: Wh->3-way frags
__global__ __launch_bounds__(256) void prep(const float* __restrict__ g,
                                            const float* __restrict__ Wo,
                                            const float* __restrict__ Whg,
                                            u32* __restrict__ adjx,
                                            u16* __restrict__ wfh,
                                            u16* __restrict__ wfm,
                                            u16* __restrict__ wfl,
                                            u16* __restrict__ whf,
                                            u16* __restrict__ whm,
                                            u16* __restrict__ whl) {
    __shared__ u8 bits[1024];
    int bx = blockIdx.x, t = threadIdx.x;
    if (bx < 1024) {
        int n = bx;
        float4 v = *(const float4*)&g[(size_t)n * 1024 + t * 4];
        bits[t * 4 + 0] = v.x != 0.0f;
        bits[t * 4 + 1] = v.y != 0.0f;
        bits[t * 4 + 2] = v.z != 0.0f;
        bits[t * 4 + 3] = v.w != 0.0f;
        __syncthreads();
        if (t < 32) {
            int r = t >> 1, h = t & 1;
            u32 wd = 0;
#pragma unroll
            for (int j = 0; j < 32; ++j)
                wd |= (u32)bits[16 * (h * 32 + j) + r] << j;
            adjx[((size_t)n * 16 + r) * 2 + h] = wd;
        }
    } else if (bx < 1056) {
        // W_out [1024][64] -> frag groups: idx = (c*32+s)*64+lane, elem j =
        // Wo[s*32+(lane>>4)*8+j][c*16+(lane&15)]
        int idx = (bx - 1024) * 256 + t;
        int lane = idx & 63, s = (idx >> 6) & 31, c = idx >> 11;
        int col = c * 16 + (lane & 15);
        int k0 = s * 32 + (lane >> 4) * 8;
        u32 hp[4], mp[4], lp[4];
#pragma unroll
        for (int jj = 0; jj < 4; ++jj) {
            float x0 = Wo[(size_t)(k0 + jj * 2 + 0) * 64 + col];
            float x1 = Wo[(size_t)(k0 + jj * 2 + 1) * 64 + col];
            u16 h0 = f2bf(x0), h1 = f2bf(x1);
            float r0 = x0 - __uint_as_float((u32)h0 << 16);
            float r1 = x1 - __uint_as_float((u32)h1 << 16);
            u16 m0 = f2bf(r0), m1 = f2bf(r1);
            float s0 = r0 - __uint_as_float((u32)m0 << 16);
            float s1 = r1 - __uint_as_float((u32)m1 << 16);
            u16 l0 = f2bf(s0), l1 = f2bf(s1);
            hp[jj] = (u32)h0 | ((u32)h1 << 16);
            mp[jj] = (u32)m0 | ((u32)m1 << 16);
            lp[jj] = (u32)l0 | ((u32)l1 << 16);
        }
        uint4 hv = {hp[0], hp[1], hp[2], hp[3]};
        uint4 mv = {mp[0], mp[1], mp[2], mp[3]};
        uint4 lv = {lp[0], lp[1], lp[2], lp[3]};
        *(uint4*)&wfh[(size_t)idx * 8] = hv;
        *(uint4*)&wfm[(size_t)idx * 8] = mv;
        *(uint4*)&wfl[(size_t)idx * 8] = lv;
    } else {
        // Wh [8][64][128] -> frag groups: idx = ((hd*8+cf)*2+ks)*64+lane,
        // elem j = Wh[hd][ks*32+(lane>>4)*8+j][cf*16+(lane&15)]
        int idx = (bx - 1056) * 256 + t;
        int lane = idx & 63, ks = (idx >> 6) & 1, cf = (idx >> 7) & 7, hd = idx >> 10;
        int col = cf * 16 + (lane & 15);
        int k0 = ks * 32 + (lane >> 4) * 8;
        const float* Wh = Whg + (size_t)hd * 64 * 128;
        u32 hp[4], mp[4], lp[4];
#pragma unroll
        for (int jj = 0; jj < 4; ++jj) {
            float x0 = Wh[(size_t)(k0 + jj * 2 + 0) * 128 + col];
            float x1 = Wh[(size_t)(k0 + jj * 2 + 1) * 128 + col];
            u16 h0 = f2bf(x0), h1 = f2bf(x1);
            float r0 = x0 - __uint_as_float((u32)h0 << 16);
            float r1 = x1 - __uint_as_float((u32)h1 << 16);
            u16 m0 = f2bf(r0), m1 = f2bf(r1);
            float s0 = r0 - __uint_as_float((u32)m0 << 16);
            float s1 = r1 - __uint_as_float((u32)m1 << 16);
            u16 l0 = f2bf(s0), l1 = f2bf(s1);
            hp[jj] = (u32)h0 | ((u32)h1 << 16);
            mp[jj] = (u32)m0 | ((u32)m1 << 16);
            lp[jj] = (u32)l0 | ((u32)l1 << 16);
        }
        uint4 hv = {hp[0], hp[1], hp[2], hp[3]};
        uint4 mv = {mp[0], mp[1], mp[2], mp[3]};
        uint4 lv = {lp[0], lp[1], lp[2], lp[3]};
        *(uint4*)&whf[(size_t)idx * 8] = hv;
        *(uint4*)&whm[(size_t)idx * 8] = mv;
        *(uint4*)&whl[(size_t)idx * 8] = lv;
    }
}

// ---------------------------------------------------------------- K1: h = x @ Wh via 3-way bf16 MFMA
// dim3(128,16) x 256: block = (bh, 64-row tile); wave = 16 rows x 128 cols.
// No LDS, no barriers. A converted in-register; B from frag-ordered wh*.
__global__ __launch_bounds__(256) void proj1m(const float* __restrict__ x,
                                              const u16* __restrict__ whf,
                                              const u16* __restrict__ whm,
                                              const u16* __restrict__ whl,
                                              float* __restrict__ hf,
                                              u16* __restrict__ hhi) {
    int bh = blockIdx.x;                 // b*8+hd
    int hd = bh & 7, bb = bh >> 3;
    int n0 = blockIdx.y * 64;
    int t = threadIdx.x, lane = t & 63, w = t >> 6;
    int l15 = lane & 15, q4 = lane >> 4;
    int arow = n0 + w * 16 + l15;
    const float* xr = x + ((size_t)bb * 1024 + arow) * 64;

    short8 axh[2], axm[2], axl[2];
#pragma unroll
    for (int ks = 0; ks < 2; ++ks) {
        float xs[8];
        *(float4*)&xs[0] = *(const float4*)&xr[ks * 32 + q4 * 8];
        *(float4*)&xs[4] = *(const float4*)&xr[ks * 32 + q4 * 8 + 4];
#pragma unroll
        for (int j = 0; j < 8; ++j) {
            u16 h = f2bf(xs[j]);
            float r1 = xs[j] - __uint_as_float((u32)h << 16);
            u16 m = f2bf(r1);
            float r2 = r1 - __uint_as_float((u32)m << 16);
            u16 l = f2bf(r2);
            axh[ks][j] = (short)h;
            axm[ks][j] = (short)m;
            axl[ks][j] = (short)l;
        }
    }

    const size_t hb = (size_t)hd * 8192;
#pragma unroll
    for (int cf = 0; cf < 8; ++cf) {
        f32x4 acc = {0.f, 0.f, 0.f, 0.f};
#pragma unroll
        for (int ks = 0; ks < 2; ++ks) {
            size_t fo = hb + (((size_t)cf * 2 + ks) * 64 + lane) * 8;
            short8 bh_ = *(const short8*)&whf[fo];
            short8 bm_ = *(const short8*)&whm[fo];
            short8 bl_ = *(const short8*)&whl[fo];
            acc = __builtin_amdgcn_mfma_f32_16x16x32_bf16(axh[ks], bh_, acc, 0, 0, 0);
            acc = __builtin_amdgcn_mfma_f32_16x16x32_bf16(axh[ks], bm_, acc, 0, 0, 0);
            acc = __builtin_amdgcn_mfma_f32_16x16x32_bf16(axm[ks], bh_, acc, 0, 0, 0);
            acc = __builtin_amdgcn_mfma_f32_16x16x32_bf16(axh[ks], bl_, acc, 0, 0, 0);
            acc = __builtin_amdgcn_mfma_f32_16x16x32_bf16(axm[ks], bm_, acc, 0, 0, 0);
            acc = __builtin_amdgcn_mfma_f32_16x16x32_bf16(axl[ks], bh_, acc, 0, 0, 0);
        }
#pragma unroll
        for (int i = 0; i < 4; ++i) {
            int ro = n0 + w * 16 + q4 * 4 + i;
            size_t a = ((size_t)bh * 1024 + ro) * 128 + cf * 16 + l15;
            hf[a] = acc[i];
            hhi[a] = f2bf(acc[i]);
        }
    }
}

// ---------------------------------------------------------------- K3: h2 = x2 @ W_out via 3-way bf16 MFMA
__global__ __launch_bounds__(256) void proj2m(const float* __restrict__ x2,
                                              const u16* __restrict__ wfh,
                                              const u16* __restrict__ wfm,
                                              const u16* __restrict__ wfl,
                                              float* __restrict__ h2f,
                                              u16* __restrict__ h2hi) {
    int bx = blockIdx.x;
    int b = bx & 15, tile = bx >> 4;
    int n0 = tile * 32;
    const float* X = x2 + ((size_t)b * 1024 + n0) * 1024;

    __shared__ __attribute__((aligned(16))) u16 Ah[2][32][40];   // +8 pad
    __shared__ __attribute__((aligned(16))) u16 Am[2][32][40];
    __shared__ __attribute__((aligned(16))) u16 Al[2][32][40];

    int t = threadIdx.x, lane = t & 63, w = t >> 6;
    int l15 = lane & 15, q4 = lane >> 4;
    int rf = w & 1, cs = w >> 1;
    int rstage = t >> 3, kseg = t & 7;

    f32x4 acc0 = {0.f, 0.f, 0.f, 0.f}, acc1 = {0.f, 0.f, 0.f, 0.f};

    auto stage = [&](int buf, const float4& xv) {
        float xs[4] = {xv.x, xv.y, xv.z, xv.w};
        u16 hh[4], mm_[4], ll[4];
#pragma unroll
        for (int j = 0; j < 4; ++j) {
            u16 h = f2bf(xs[j]);
            float r1 = xs[j] - __uint_as_float((u32)h << 16);
            u16 m = f2bf(r1);
            float r2 = r1 - __uint_as_float((u32)m << 16);
            u16 l = f2bf(r2);
            hh[j] = h; mm_[j] = m; ll[j] = l;
        }
        uint2 hp = {(u32)hh[0] | ((u32)hh[1] << 16), (u32)hh[2] | ((u32)hh[3] << 16)};
        uint2 mp = {(u32)mm_[0] | ((u32)mm_[1] << 16), (u32)mm_[2] | ((u32)mm_[3] << 16)};
        uint2 lp = {(u32)ll[0] | ((u32)ll[1] << 16), (u32)ll[2] | ((u32)ll[3] << 16)};
        *(uint2*)&Ah[buf][rstage][kseg * 4] = hp;
        *(uint2*)&Am[buf][rstage][kseg * 4] = mp;
        *(uint2*)&Al[buf][rstage][kseg * 4] = lp;
    };

    float4 xv0 = *(const float4*)&X[(size_t)rstage * 1024 + kseg * 4];
    stage(0, xv0);
    float4 xva = *(const float4*)&X[(size_t)rstage * 1024 + 32 + kseg * 4];
    float4 xvb = *(const float4*)&X[(size_t)rstage * 1024 + 64 + kseg * 4];

    for (int s = 0; s < 32; ++s) {
        __syncthreads();                   // tile s staged & visible
        int buf = s & 1;
        if (s < 31) {
            stage(buf ^ 1, xva);           // stage tile s+1
            xva = xvb;
            if (s < 30)
                xvb = *(const float4*)&X[(size_t)rstage * 1024 + (s + 3) * 32 + kseg * 4];
        }
        short8 ah = *(const short8*)&Ah[buf][rf * 16 + l15][q4 * 8];
        short8 am = *(const short8*)&Am[buf][rf * 16 + l15][q4 * 8];
        short8 al = *(const short8*)&Al[buf][rf * 16 + l15][q4 * 8];
        size_t f0 = ((size_t)((cs * 2 + 0) * 32 + s) * 64 + lane) * 8;
        size_t f1 = ((size_t)((cs * 2 + 1) * 32 + s) * 64 + lane) * 8;
        short8 bh0 = *(const short8*)&wfh[f0];
        short8 bm0 = *(const short8*)&wfm[f0];
        short8 bl0 = *(const short8*)&wfl[f0];
        short8 bh1 = *(const short8*)&wfh[f1];
        short8 bm1 = *(const short8*)&wfm[f1];
        short8 bl1 = *(const short8*)&wfl[f1];
        acc0 = __builtin_amdgcn_mfma_f32_16x16x32_bf16(ah, bh0, acc0, 0, 0, 0);
        acc0 = __builtin_amdgcn_mfma_f32_16x16x32_bf16(ah, bm0, acc0, 0, 0, 0);
        acc0 = __builtin_amdgcn_mfma_f32_16x16x32_bf16(am, bh0, acc0, 0, 0, 0);
        acc0 = __builtin_amdgcn_mfma_f32_16x16x32_bf16(ah, bl0, acc0, 0, 0, 0);
        acc0 = __builtin_amdgcn_mfma_f32_16x16x32_bf16(am, bm0, acc0, 0, 0, 0);
        acc0 = __builtin_amdgcn_mfma_f32_16x16x32_bf16(al, bh0, acc0, 0, 0, 0);
        acc1 = __builtin_amdgcn_mfma_f32_16x16x32_bf16(ah, bh1, acc1, 0, 0, 0);
        acc1 = __builtin_amdgcn_mfma_f32_16x16x32_bf16(ah, bm1, acc1, 0, 0, 0);
        acc1 = __builtin_amdgcn_mfma_f32_16x16x32_bf16(am, bh1, acc1, 0, 0, 0);
        acc1 = __builtin_amdgcn_mfma_f32_16x16x32_bf16(ah, bl1, acc1, 0, 0, 0);
        acc1 = __builtin_amdgcn_mfma_f32_16x16x32_bf16(am, bm1, acc1, 0, 0, 0);
        acc1 = __builtin_amdgcn_mfma_f32_16x16x32_bf16(al, bh1, acc1, 0, 0, 0);
    }

    // C frag: col = lane&15, row = q4*4 + i
#pragma unroll
    for (int i = 0; i < 4; ++i) {
        int row = n0 + rf * 16 + q4 * 4 + i;
        size_t a0 = ((size_t)b * 1024 + row) * 64 + (cs * 2 + 0) * 16 + l15;
        size_t a1 = ((size_t)b * 1024 + row) * 64 + (cs * 2 + 1) * 16 + l15;
        h2f[a0] = acc0[i];  h2hi[a0] = f2bf(acc0[i]);
        h2f[a1] = acc1[i];  h2hi[a1] = f2bf(acc1[i]);
    }
}

// ---------------------------------------------------------------- K2: L1 fused masked attention (round-19, control)
template <int DK, int NH, int ORS, int RT>
__global__ __launch_bounds__(256, 4) void attn6(const u16* __restrict__ hhi,
                                                const float* __restrict__ hf,
                                                const u32* __restrict__ adjx,
                                                const float* __restrict__ bias,
                                                float* __restrict__ outp) {
    constexpr int CR   = DK / 8;
    constexpr int NC   = DK / 32;
    constexpr int LGCR = (CR == 16) ? 4 : 3;
    constexpr int RPI  = 64 / CR;
    constexpr int NI   = 16 / RPI;
    constexpr int RW   = RT / 4;
    constexpr int RS   = RW / 16;
    constexpr int NBH  = NH * 16;
    constexpr int CMAX = 16;
    constexpr int HBUF = 64 * DK;         // u16 per staging buffer
    const u32 NEGK = 0xFF800000u;

    int bx = blockIdx.x;
    int bh = bx % NBH, tile = bx / NBH;   // XCD swizzle: bx%8 == bh%8
    int hd = (NH == 1) ? 0 : (bh & (NH - 1));
    int b  = (NH == 1) ? bh : (bh >> 3);
    int n0 = tile * RT;
    const u16*   Hhi = hhi + (size_t)bh * 1024 * DK;
    const float* Hf  = hf  + (size_t)bh * 1024 * DK;
    const float* bs  = bias + (size_t)hd * DK;
    float* ob = outp + (size_t)b * 1024 * ORS + (size_t)hd * DK;

    __shared__ __attribute__((aligned(16))) char smem[2 * HBUF * 2];   // 32768 B
    u16* Ksh = (u16*)smem;
    int   (*candm)[CMAX] = (int(*)[CMAX])smem;               // 8 KB @ 0
    float (*cands)[CMAX] = (float(*)[CMAX])(smem + 8192);    // 8 KB @ 8K
    int*   cnt           = (int*)(smem + 16384);             // 512 B @ 16K
    int*   wl            = (int*)(smem + 16896);             // 8 KB @ 16.5K
    int*   wln           = (int*)(smem + 25088);             // 4 B

    int t = threadIdx.x, lane = t & 63, w = t >> 6;
    int l15 = lane & 15, q4 = lane >> 4;

    uint2 adm[RS][4];
#pragma unroll
    for (int rs = 0; rs < RS; ++rs)
#pragma unroll
        for (int rg = 0; rg < 4; ++rg) {
            int row = w * RW + rs * 16 + q4 * 4 + rg;
            adm[rs][rg] = *(const uint2*)&adjx[((size_t)(n0 + row) * 16 + l15) * 2];
        }

    short8 af[RS][NC];
#pragma unroll
    for (int rs = 0; rs < RS; ++rs) {
        int ar = n0 + w * RW + rs * 16 + l15;
#pragma unroll
        for (int c = 0; c < NC; ++c)
            af[rs][c] = *(const short8*)&Hhi[(size_t)ar * DK + c * 32 + q4 * 8];
    }

    int mb = w * 16 + (lane >> LGCR);
    int sl = lane & (CR - 1);
    u32 goff[NI];
#pragma unroll
    for (int i = 0; i < NI; ++i) {
        int m = mb + i * RPI;
        goff[i] = (u32)(m * DK + ((sl ^ (m & (CR - 1))) << 3));
    }

    float t0[RS][4], t1[RS][4];
#pragma unroll
    for (int rs = 0; rs < RS; ++rs)
#pragma unroll
        for (int rg = 0; rg < 4; ++rg) {
            t0[rs][rg] = __uint_as_float(NEGK);
            t1[rs][rg] = __uint_as_float(NEGK);
        }

    {
        const u16* gp = Hhi;
#pragma unroll
        for (int i = 0; i < NI; ++i)
            __builtin_amdgcn_global_load_lds(
                (const GLOBAL_AS u32*)(gp + goff[i]),
                (LDS_AS u32*)&Ksh[w * 16 * DK + i * 512], 16, 0, 0);
    }
    for (int m0 = 0; m0 < 1024; m0 += 64) {
        int buf = (m0 >> 6) & 1;
        if (m0 + 64 < 1024) {
            const u16* gp = Hhi + (size_t)(m0 + 64) * DK;
#pragma unroll
            for (int i = 0; i < NI; ++i)
                __builtin_amdgcn_global_load_lds(
                    (const GLOBAL_AS u32*)(gp + goff[i]),
                    (LDS_AS u32*)&Ksh[(buf ^ 1) * HBUF + w * 16 * DK + i * 512], 16, 0, 0);
            asm volatile("s_waitcnt vmcnt(4)" ::: "memory");
        } else {
            asm volatile("s_waitcnt vmcnt(0)" ::: "memory");
        }
        __builtin_amdgcn_sched_barrier(0);
        asm volatile("s_barrier" ::: "memory");       // RAW: everyone's tile t landed

        const u16* Kb = Ksh + buf * HBUF;
        int J0 = m0 >> 4, shb = J0 & 31;
        u32 wmsel[RS][4];
#pragma unroll
        for (int rs = 0; rs < RS; ++rs)
#pragma unroll
            for (int rg = 0; rg < 4; ++rg)
                wmsel[rs][rg] = (J0 & 32) ? adm[rs][rg].y : adm[rs][rg].x;
#pragma unroll
        for (int mt = 0; mt < 4; ++mt) {
            int mrow = mt * 16 + l15;
            short8 bf[NC];
#pragma unroll
            for (int c = 0; c < NC; ++c) {
                int slot = (c * 4 + q4) ^ (mrow & (CR - 1));
                bf[c] = *(const short8*)&Kb[mrow * DK + slot * 8];
            }
            int jcol = m0 + mt * 16 + l15;
#pragma unroll
            for (int rs = 0; rs < RS; ++rs) {
                f32x4 acc = {0.f, 0.f, 0.f, 0.f};
#pragma unroll
                for (int c = 0; c < NC; ++c)
                    acc = __builtin_amdgcn_mfma_f32_16x16x32_bf16(af[rs][c], bf[c], acc, 0, 0, 0);
#pragma unroll
                for (int rg = 0; rg < 4; ++rg) {
                    u32 pk = (__float_as_uint(acc[rg]) & 0xFFFFFC00u) | (u32)jcol; // v_and_or
                    u32 msk = (u32)__builtin_amdgcn_sbfe((int)wmsel[rs][rg], shb + mt, 1);
                    u32 pmu = (pk & msk) | (NEGK & ~msk);                          // v_bfi
                    float tf = __uint_as_float(pmu);
                    t1[rs][rg] = __builtin_amdgcn_fmed3f(tf, t0[rs][rg], t1[rs][rg]);
                    t0[rs][rg] = fmaxf(t0[rs][rg], tf);
                }
            }
        }
        asm volatile("s_barrier" ::: "memory");       // WAR: all waves done with buf
    }
    __syncthreads();                       // all staging dead; aliases usable
    for (int u = t; u < RT; u += 256) cnt[u] = 0;
    if (t == 0) *wln = 0;
    __syncthreads();

#pragma unroll
    for (int rs = 0; rs < RS; ++rs)
#pragma unroll
        for (int rg = 0; rg < 4; ++rg) {
            float m = t0[rs][rg];
#pragma unroll
            for (int off = 1; off < 16; off <<= 1) m = fmaxf(m, __shfl_xor(m, off));
            float thr = m - (100.0f + 0.04f * fabsf(m));
            int row = w * RW + rs * 16 + q4 * 4 + rg;
            if (t0[rs][rg] > thr) {
                int p = atomicAdd(&cnt[row], 1);
                if (p < CMAX) candm[row][p] = (int)(__float_as_uint(t0[rs][rg]) & 1023u);
            }
            if (t1[rs][rg] > thr) {
                int p = atomicAdd(&cnt[row], 1);
                if (p < CMAX) candm[row][p] = (int)(__float_as_uint(t1[rs][rg]) & 1023u);
            }
        }
    __syncthreads();

    // compact (row,ci) worklist
    if (t < RT) {
        int kc = cnt[t]; if (kc > CMAX) kc = CMAX;
        int base = atomicAdd(wln, kc);
        for (int i = 0; i < kc; ++i) wl[base + i] = (t << 4) | i;
    }
    __syncthreads();

    // exact fp32 dots: one 8-lane group per candidate, coalesced 128B segments
    {
        int M = *wln;
        int g = t >> 3, l = t & 7;
        for (int e = g; e < M; e += 32) {
            int pk = wl[e];
            int row = pk >> 4, ci = pk & 15;
            const float* qa = Hf + (size_t)(n0 + row) * DK + l * (DK / 8);
            const float* kb = Hf + (size_t)candm[row][ci] * DK + l * (DK / 8);
            float acc = 0.f;
#pragma unroll
            for (int d = 0; d < DK / 8; d += 4) {
                float4 a  = *(const float4*)&qa[d];
                float4 bv = *(const float4*)&kb[d];
                acc += a.x * bv.x + a.y * bv.y + a.z * bv.z + a.w * bv.w;
            }
            acc += __shfl_xor(acc, 4);
            acc += __shfl_xor(acc, 2);
            acc += __shfl_xor(acc, 1);
            if (l == 0) cands[row][ci] = acc;
        }
    }
    __syncthreads();

    for (int row = t; row < RT; row += 256) {
        int kc = cnt[row]; if (kc > CMAX) kc = CMAX;
        float M = -3e38f;
        for (int i = 0; i < kc; ++i) M = fmaxf(M, cands[row][i]);
        float L = 0.f;
        for (int i = 0; i < kc; ++i) { float p = expf(cands[row][i] - M); cands[row][i] = p; L += p; }
        float inv = 1.f / L;
        for (int i = 0; i < kc; ++i) cands[row][i] *= inv;
    }
    __syncthreads();

    constexpr int D4 = DK / 4;
    for (int e = t; e < RT * D4; e += 256) {
        int row = e / D4, d4 = (e % D4) * 4;
        int kc = cnt[row]; if (kc > CMAX) kc = CMAX;
        float4 o = *(const float4*)&bs[d4];
        for (int i = 0; i < kc; ++i) {
            float p = cands[row][i];
            const float4 hv = *(const float4*)&Hf[(size_t)candm[row][i] * DK + d4];
            o.x += p * hv.x; o.y += p * hv.y; o.z += p * hv.z; o.w += p * hv.w;
        }
        o.x = o.x > 0.f ? o.x : 0.01f * o.x;
        o.y = o.y > 0.f ? o.y : 0.01f * o.y;
        o.z = o.z > 0.f ? o.z : 0.01f * o.z;
        o.w = o.w > 0.f ? o.w : 0.01f * o.w;
        *(float4*)&ob[(size_t)(n0 + row) * ORS + d4] = o;
    }
}

// ---------------------------------------------------------------- K4: L2 fused masked attention
__global__ __launch_bounds__(256) void attn6w(const u16* __restrict__ hhi,
                                              const float* __restrict__ hf,
                                              const u32* __restrict__ adjx,
                                              const float* __restrict__ bias,
                                              float* __restrict__ outp) {
    constexpr int DK = 64, NC = 2, CMAX = 16;
    constexpr int QR = 128;
    constexpr int HBUF = QR * DK;
    const u32 NEGK = 0xFF800000u;

    int bx = blockIdx.x;
    int b = bx & 15, tile = bx >> 4;
    int n0 = tile * 64;
    const u16*   Hhi = hhi + (size_t)b * 1024 * DK;
    const float* Hf  = hf  + (size_t)b * 1024 * DK;
    float* ob = outp + (size_t)b * 1024 * 64;

    __shared__ __attribute__((aligned(16))) u16 Ksh[2 * HBUF];
    int   (*candm)[CMAX] = (int(*)[CMAX])Ksh;                // 4 KB @ 0
    float (*cands)[CMAX] = (float(*)[CMAX])(Ksh + 2048);     // 4 KB @ 4K
    int* cnt = (int*)(Ksh + 4096);                           // 256 B @ 8K
    int* wl  = (int*)(Ksh + 4224);                           // 4 KB @ 8.25K
    int* wln = (int*)(Ksh + 6272);                           // 4 B @ 12.25K

    int t = threadIdx.x, lane = t & 63, w = t >> 6;
    int l15 = lane & 15, q4 = lane >> 4;

    uint2 adm[4];
#pragma unroll
    for (int rg = 0; rg < 4; ++rg) {
        int row = w * 16 + q4 * 4 + rg;
        adm[rg] = *(const uint2*)&adjx[((size_t)(n0 + row) * 16 + l15) * 2];
    }

    short8 af[NC];
    {
        int ar = n0 + w * 16 + l15;
#pragma unroll
        for (int c = 0; c < NC; ++c)
            af[c] = *(const short8*)&Hhi[(size_t)ar * DK + c * 32 + q4 * 8];
    }

    u32 goff[4];
#pragma unroll
    for (int i = 0; i < 4; ++i) {
        int q = i * 64 + lane;
        int lr = w * 32 + (q >> 3);
        int sl = q & 7;
        goff[i] = (u32)(lr * DK + ((sl ^ (lr & 7)) << 3));
    }

    float t0[4], t1[4];
#pragma unroll
    for (int rg = 0; rg < 4; ++rg) { t0[rg] = __uint_as_float(NEGK); t1[rg] = __uint_as_float(NEGK); }

#pragma unroll
    for (int i = 0; i < 4; ++i)
        __builtin_amdgcn_global_load_lds(
            (const GLOBAL_AS u32*)(Hhi + goff[i]),
            (LDS_AS u32*)&Ksh[w * 32 * DK + i * 512], 16, 0, 0);

    for (int s = 0; s < 8; ++s) {
        __syncthreads();
        if (s < 7) {
            const u16* gp = Hhi + (size_t)(s + 1) * QR * DK;
            int obuf = (s + 1) & 1;
#pragma unroll
            for (int i = 0; i < 4; ++i)
                __builtin_amdgcn_global_load_lds(
                    (const GLOBAL_AS u32*)(gp + goff[i]),
                    (LDS_AS u32*)&Ksh[obuf * HBUF + w * 32 * DK + i * 512], 16, 0, 0);
        }
        const u16* Kb = Ksh + (s & 1) * HBUF;
#pragma unroll
        for (int mq = 0; mq < 2; ++mq) {
            int m0 = s * QR + mq * 64;
            int J0 = m0 >> 4, shb = J0 & 31;
            u32 wmsel[4];
#pragma unroll
            for (int rg = 0; rg < 4; ++rg) wmsel[rg] = (J0 & 32) ? adm[rg].y : adm[rg].x;
#pragma unroll
            for (int mt = 0; mt < 4; ++mt) {
                int mloc = mq * 64 + mt * 16 + l15;
                short8 bf[NC];
#pragma unroll
                for (int c = 0; c < NC; ++c) {
                    int slot = (c * 4 + q4) ^ (mloc & 7);
                    bf[c] = *(const short8*)&Kb[mloc * DK + slot * 8];
                }
                int jcol = m0 + mt * 16 + l15;
                f32x4 acc = {0.f, 0.f, 0.f, 0.f};
#pragma unroll
                for (int c = 0; c < NC; ++c)
                    acc = __builtin_amdgcn_mfma_f32_16x16x32_bf16(af[c], bf[c], acc, 0, 0, 0);
#pragma unroll
                for (int rg = 0; rg < 4; ++rg) {
                    u32 pk = (__float_as_uint(acc[rg]) & 0xFFFFFC00u) | (u32)jcol;
                    u32 msk = (u32)__builtin_amdgcn_sbfe((int)wmsel[rg], shb + mt, 1);
                    u32 pmu = (pk & msk) | (NEGK & ~msk);
                    float tf = __uint_as_float(pmu);
                    t1[rg] = __builtin_amdgcn_fmed3f(tf, t0[rg], t1[rg]);
                    t0[rg] = fmaxf(t0[rg], tf);
                }
            }
        }
    }
    __syncthreads();
    if (t < 64) cnt[t] = 0;
    if (t == 0) *wln = 0;
    __syncthreads();

#pragma unroll
    for (int rg = 0; rg < 4; ++rg) {
        float m = t0[rg];
#pragma unroll
        for (int off = 1; off < 16; off <<= 1) m = fmaxf(m, __shfl_xor(m, off));
        float thr = m - (100.0f + 0.04f * fabsf(m));
        int row = w * 16 + q4 * 4 + rg;
        if (t0[rg] > thr) {
            int p = atomicAdd(&cnt[row], 1);
            if (p < CMAX) candm[row][p] = (int)(__float_as_uint(t0[rg]) & 1023u);
        }
        if (t1[rg] > thr) {
            int p = atomicAdd(&cnt[row], 1);
            if (p < CMAX) candm[row][p] = (int)(__float_as_uint(t1[rg]) & 1023u);
        }
    }
    __syncthreads();

    // compact (row,ci) worklist
    if (t < 64) {
        int kc = cnt[t]; if (kc > CMAX) kc = CMAX;
        int base = atomicAdd(wln, kc);
        for (int i = 0; i < kc; ++i) wl[base + i] = (t << 4) | i;
    }
    __syncthreads();

    // exact fp32 dots: one 8-lane group per candidate
    {
        int M = *wln;
        int g = t >> 3, l = t & 7;
        for (int e = g; e < M; e += 32) {
            int pk = wl[e];
            int row = pk >> 4, ci = pk & 15;
            const float* qa = Hf + (size_t)(n0 + row) * DK + l * (DK / 8);
            const float* kb = Hf + (size_t)candm[row][ci] * DK + l * (DK / 8);
            float acc = 0.f;
#pragma unroll
            for (int d = 0; d < DK / 8; d += 4) {
                float4 a  = *(const float4*)&qa[d];
                float4 bv = *(const float4*)&kb[d];
                acc += a.x * bv.x + a.y * bv.y + a.z * bv.z + a.w * bv.w;
            }
            acc += __shfl_xor(acc, 4);
            acc += __shfl_xor(acc, 2);
            acc += __shfl_xor(acc, 1);
            if (l == 0) cands[row][ci] = acc;
        }
    }
    __syncthreads();

    if (t < 64) {
        int row = t;
        int kc = cnt[row]; if (kc > CMAX) kc = CMAX;
        float M = -3e38f;
        for (int i = 0; i < kc; ++i) M = fmaxf(M, cands[row][i]);
        float L = 0.f;
        for (int i = 0; i < kc; ++i) { float p = expf(cands[row][i] - M); cands[row][i] = p; L += p; }
        float inv = 1.f / L;
        for (int i = 0; i < kc; ++i) cands[row][i] *= inv;
    }
    __syncthreads();

    for (int e = t; e < 64 * 16; e += 256) {
        int row = e / 16, d4 = (e % 16) * 4;
        int kc = cnt[row]; if (kc > CMAX) kc = CMAX;
        float4 o = *(const float4*)&bias[d4];
        for (int i = 0; i < kc; ++i) {
            float p = cands[row][i];
            const float4 hv = *(const float4*)&Hf[(size_t)candm[row][i] * DK + d4];
            o.x += p * hv.x; o.y += p * hv.y; o.z += p * hv.z; o.w += p * hv.w;
        }
        o.x = o.x > 0.f ? o.x : 0.01f * o.x;
        o.y = o.y > 0.f ? o.y : 0.01f * o.y;
        o.z = o.z > 0.f ? o.z : 0.01f * o.z;
        o.w = o.w > 0.f ? o.w : 0.01f * o.w;
        *(float4*)&ob[(size_t)(n0 + row) * 64 + d4] = o;
    }
}

// ---------------------------------------------------------------- launcher
extern "C" void kernel_launch(void* const* d_in, const int* in_sizes, int n_in,
                              void* d_out, int out_size, void* d_ws, size_t ws_size,
                              hipStream_t stream) {
    (void)in_sizes; (void)n_in; (void)out_size; (void)ws_size;
    const float* flow_x = (const float*)d_in[0];   // [16,1024,64]
    const float* graph  = (const float*)d_in[1];   // [1024,1024]
    const float* Wh     = (const float*)d_in[2];   // [8,64,128]
    const float* bh     = (const float*)d_in[3];   // [8,128]
    const float* W_out  = (const float*)d_in[4];   // [1024,64]
    const float* b_out  = (const float*)d_in[5];   // [64]
    float* out = (float*)d_out;                    // [16,1024,64] fp32

    // workspace carve-up (~168 MB; all 16B-aligned)
    float* h_f32 = (float*)d_ws;                       // 16,777,216 f  [bh][n][128]
    float* x2    = h_f32 + 16777216;                   // 16,777,216 f  [b][n][1024]
    float* h2    = x2 + 16777216;                      //  1,048,576 f  [b][n][64]
    u16*  h_hi   = (u16*)(h2 + 1048576);               // 16,777,216 u16
    u16*  h2_hi  = h_hi + 16777216;                    //  1,048,576 u16
    u32*  adjx   = (u32*)(h2_hi + 1048576);            //     32,768 u32 (residue-bucketed)
    u16*  wfh    = (u16*)(adjx + 32768);               //     65,536 u16 (W_out hi frags)
    u16*  wfm    = wfh + 65536;                        //     65,536 u16 (W_out mid frags)
    u16*  wfl    = wfm + 65536;                        //     65,536 u16 (W_out lo frags)
    u16*  whf    = wfl + 65536;                        //     65,536 u16 (Wh hi frags)
    u16*  whm    = whf + 65536;                        //     65,536 u16 (Wh mid frags)
    u16*  whl    = whm + 65536;                        //     65,536 u16 (Wh lo frags)

    prep<<<1088, 256, 0, stream>>>(graph, W_out, Wh, adjx, wfh, wfm, wfl, whf, whm, whl);
    proj1m<<<dim3(128, 16), 256, 0, stream>>>(flow_x, whf, whm, whl, h_f32, h_hi);
    attn6<128, 8, 1024, 128><<<1024, 256, 0, stream>>>(h_hi, h_f32, adjx, bh, x2);
    proj2m<<<512, 256, 0, stream>>>(x2, wfh, wfm, wfl, h2, h2_hi);
    attn6w<<<256, 256, 0, stream>>>(h2_hi, h2, adjx, b_out, out);
}

// Round 8
// 223.846 us; speedup vs baseline: 1.2069x; 1.0466x over previous
//
#include <hip/hip_runtime.h>
#include <cstdint>
#include <cstddef>

// GATNet on MI355X — round 21.
// Base = round 20 (234.3us): proj1m + proj2m 3-way bf16 MFMA GEMMs, attn6
// round-19 (94.3us control), merged prep.
// Round-21 change (proj2m ONLY): re-tile from 32-row blocks (512 blocks =
// 2 blocks/CU = 2 waves/SIMD, occupancy-starved barrier loop) to 16-row
// blocks (1024 blocks = 4 blocks/CU = 16 waves/CU). Wave w owns colfrag w;
// per iter: 3 A ds_reads + 3 B global (L2) loads + 6 MFMA. Same product
// set/order -> numerics identical. x2 traffic unchanged.

typedef short short8 __attribute__((ext_vector_type(8)));
typedef float f32x4  __attribute__((ext_vector_type(4)));
typedef unsigned short u16;
typedef unsigned char  u8;
typedef unsigned int   u32;

#define GLOBAL_AS __attribute__((address_space(1)))
#define LDS_AS    __attribute__((address_space(3)))

__device__ __forceinline__ u16 f2bf(float f) {        // RNE float->bf16 bits
    u32 x = __float_as_uint(f);
    u32 r = (x + 0x7FFFu + ((x >> 16) & 1u)) >> 16;
    return (u16)r;
}

// ---------------------------------------------------------------- K0: prep
// bx<1024: graph->bitmasks; 1024..1055: W_out->3-way frags; 1056..1087: Wh->3-way frags
__global__ __launch_bounds__(256) void prep(const float* __restrict__ g,
                                            const float* __restrict__ Wo,
                                            const float* __restrict__ Whg,
                                            u32* __restrict__ adjx,
                                            u16* __restrict__ wfh,
                                            u16* __restrict__ wfm,
                                            u16* __restrict__ wfl,
                                            u16* __restrict__ whf,
                                            u16* __restrict__ whm,
                                            u16* __restrict__ whl) {
    __shared__ u8 bits[1024];
    int bx = blockIdx.x, t = threadIdx.x;
    if (bx < 1024) {
        int n = bx;
        float4 v = *(const float4*)&g[(size_t)n * 1024 + t * 4];
        bits[t * 4 + 0] = v.x != 0.0f;
        bits[t * 4 + 1] = v.y != 0.0f;
        bits[t * 4 + 2] = v.z != 0.0f;
        bits[t * 4 + 3] = v.w != 0.0f;
        __syncthreads();
        if (t < 32) {
            int r = t >> 1, h = t & 1;
            u32 wd = 0;
#pragma unroll
            for (int j = 0; j < 32; ++j)
                wd |= (u32)bits[16 * (h * 32 + j) + r] << j;
            adjx[((size_t)n * 16 + r) * 2 + h] = wd;
        }
    } else if (bx < 1056) {
        int idx = (bx - 1024) * 256 + t;
        int lane = idx & 63, s = (idx >> 6) & 31, c = idx >> 11;
        int col = c * 16 + (lane & 15);
        int k0 = s * 32 + (lane >> 4) * 8;
        u32 hp[4], mp[4], lp[4];
#pragma unroll
        for (int jj = 0; jj < 4; ++jj) {
            float x0 = Wo[(size_t)(k0 + jj * 2 + 0) * 64 + col];
            float x1 = Wo[(size_t)(k0 + jj * 2 + 1) * 64 + col];
            u16 h0 = f2bf(x0), h1 = f2bf(x1);
            float r0 = x0 - __uint_as_float((u32)h0 << 16);
            float r1 = x1 - __uint_as_float((u32)h1 << 16);
            u16 m0 = f2bf(r0), m1 = f2bf(r1);
            float s0 = r0 - __uint_as_float((u32)m0 << 16);
            float s1 = r1 - __uint_as_float((u32)m1 << 16);
            u16 l0 = f2bf(s0), l1 = f2bf(s1);
            hp[jj] = (u32)h0 | ((u32)h1 << 16);
            mp[jj] = (u32)m0 | ((u32)m1 << 16);
            lp[jj] = (u32)l0 | ((u32)l1 << 16);
        }
        uint4 hv = {hp[0], hp[1], hp[2], hp[3]};
        uint4 mv = {mp[0], mp[1], mp[2], mp[3]};
        uint4 lv = {lp[0], lp[1], lp[2], lp[3]};
        *(uint4*)&wfh[(size_t)idx * 8] = hv;
        *(uint4*)&wfm[(size_t)idx * 8] = mv;
        *(uint4*)&wfl[(size_t)idx * 8] = lv;
    } else {
        int idx = (bx - 1056) * 256 + t;
        int lane = idx & 63, ks = (idx >> 6) & 1, cf = (idx >> 7) & 7, hd = idx >> 10;
        int col = cf * 16 + (lane & 15);
        int k0 = ks * 32 + (lane >> 4) * 8;
        const float* Wh = Whg + (size_t)hd * 64 * 128;
        u32 hp[4], mp[4], lp[4];
#pragma unroll
        for (int jj = 0; jj < 4; ++jj) {
            float x0 = Wh[(size_t)(k0 + jj * 2 + 0) * 128 + col];
            float x1 = Wh[(size_t)(k0 + jj * 2 + 1) * 128 + col];
            u16 h0 = f2bf(x0), h1 = f2bf(x1);
            float r0 = x0 - __uint_as_float((u32)h0 << 16);
            float r1 = x1 - __uint_as_float((u32)h1 << 16);
            u16 m0 = f2bf(r0), m1 = f2bf(r1);
            float s0 = r0 - __uint_as_float((u32)m0 << 16);
            float s1 = r1 - __uint_as_float((u32)m1 << 16);
            u16 l0 = f2bf(s0), l1 = f2bf(s1);
            hp[jj] = (u32)h0 | ((u32)h1 << 16);
            mp[jj] = (u32)m0 | ((u32)m1 << 16);
            lp[jj] = (u32)l0 | ((u32)l1 << 16);
        }
        uint4 hv = {hp[0], hp[1], hp[2], hp[3]};
        uint4 mv = {mp[0], mp[1], mp[2], mp[3]};
        uint4 lv = {lp[0], lp[1], lp[2], lp[3]};
        *(uint4*)&whf[(size_t)idx * 8] = hv;
        *(uint4*)&whm[(size_t)idx * 8] = mv;
        *(uint4*)&whl[(size_t)idx * 8] = lv;
    }
}

// ---------------------------------------------------------------- K1: h = x @ Wh via 3-way bf16 MFMA
__global__ __launch_bounds__(256) void proj1m(const float* __restrict__ x,
                                              const u16* __restrict__ whf,
                                              const u16* __restrict__ whm,
                                              const u16* __restrict__ whl,
                                              float* __restrict__ hf,
                                              u16* __restrict__ hhi) {
    int bh = blockIdx.x;                 // b*8+hd
    int hd = bh & 7, bb = bh >> 3;
    int n0 = blockIdx.y * 64;
    int t = threadIdx.x, lane = t & 63, w = t >> 6;
    int l15 = lane & 15, q4 = lane >> 4;
    int arow = n0 + w * 16 + l15;
    const float* xr = x + ((size_t)bb * 1024 + arow) * 64;

    short8 axh[2], axm[2], axl[2];
#pragma unroll
    for (int ks = 0; ks < 2; ++ks) {
        float xs[8];
        *(float4*)&xs[0] = *(const float4*)&xr[ks * 32 + q4 * 8];
        *(float4*)&xs[4] = *(const float4*)&xr[ks * 32 + q4 * 8 + 4];
#pragma unroll
        for (int j = 0; j < 8; ++j) {
            u16 h = f2bf(xs[j]);
            float r1 = xs[j] - __uint_as_float((u32)h << 16);
            u16 m = f2bf(r1);
            float r2 = r1 - __uint_as_float((u32)m << 16);
            u16 l = f2bf(r2);
            axh[ks][j] = (short)h;
            axm[ks][j] = (short)m;
            axl[ks][j] = (short)l;
        }
    }

    const size_t hb = (size_t)hd * 8192;
#pragma unroll
    for (int cf = 0; cf < 8; ++cf) {
        f32x4 acc = {0.f, 0.f, 0.f, 0.f};
#pragma unroll
        for (int ks = 0; ks < 2; ++ks) {
            size_t fo = hb + (((size_t)cf * 2 + ks) * 64 + lane) * 8;
            short8 bh_ = *(const short8*)&whf[fo];
            short8 bm_ = *(const short8*)&whm[fo];
            short8 bl_ = *(const short8*)&whl[fo];
            acc = __builtin_amdgcn_mfma_f32_16x16x32_bf16(axh[ks], bh_, acc, 0, 0, 0);
            acc = __builtin_amdgcn_mfma_f32_16x16x32_bf16(axh[ks], bm_, acc, 0, 0, 0);
            acc = __builtin_amdgcn_mfma_f32_16x16x32_bf16(axm[ks], bh_, acc, 0, 0, 0);
            acc = __builtin_amdgcn_mfma_f32_16x16x32_bf16(axh[ks], bl_, acc, 0, 0, 0);
            acc = __builtin_amdgcn_mfma_f32_16x16x32_bf16(axm[ks], bm_, acc, 0, 0, 0);
            acc = __builtin_amdgcn_mfma_f32_16x16x32_bf16(axl[ks], bh_, acc, 0, 0, 0);
        }
#pragma unroll
        for (int i = 0; i < 4; ++i) {
            int ro = n0 + w * 16 + q4 * 4 + i;
            size_t a = ((size_t)bh * 1024 + ro) * 128 + cf * 16 + l15;
            hf[a] = acc[i];
            hhi[a] = f2bf(acc[i]);
        }
    }
}

// ---------------------------------------------------------------- K3: h2 = x2 @ W_out via 3-way bf16 MFMA
// Round-21: 16-row tiles, grid 1024 (4 blocks/CU, 16 waves/CU). Wave w owns
// colfrag w (cols w*16..+15). A tile [16][32] 3-way split in LDS (7.7KB,
// double-buffered); B from frag-ordered wf* (L2). Same 6-product order as
// round-17 -> numerics identical.
__global__ __launch_bounds__(256) void proj2m(const float* __restrict__ x2,
                                              const u16* __restrict__ wfh,
                                              const u16* __restrict__ wfm,
                                              const u16* __restrict__ wfl,
                                              float* __restrict__ h2f,
                                              u16* __restrict__ h2hi) {
    int bx = blockIdx.x;
    int b = bx & 15, tile = bx >> 4;     // 64 tiles of 16 rows
    int n0 = tile * 16;
    const float* X = x2 + ((size_t)b * 1024 + n0) * 1024;

    __shared__ __attribute__((aligned(16))) u16 Ah[2][16][40];   // +8 pad
    __shared__ __attribute__((aligned(16))) u16 Am[2][16][40];
    __shared__ __attribute__((aligned(16))) u16 Al[2][16][40];

    int t = threadIdx.x, lane = t & 63, w = t >> 6;
    int l15 = lane & 15, q4 = lane >> 4;
    int rstage = t >> 4, k2 = (t & 15) * 2;     // thread -> (row, 2 k-elems)

    f32x4 acc = {0.f, 0.f, 0.f, 0.f};

    auto stage = [&](int buf, const float2& xv) {
        float xs[2] = {xv.x, xv.y};
        u16 hh[2], mm_[2], ll[2];
#pragma unroll
        for (int j = 0; j < 2; ++j) {
            u16 h = f2bf(xs[j]);
            float r1 = xs[j] - __uint_as_float((u32)h << 16);
            u16 m = f2bf(r1);
            float r2 = r1 - __uint_as_float((u32)m << 16);
            u16 l = f2bf(r2);
            hh[j] = h; mm_[j] = m; ll[j] = l;
        }
        *(u32*)&Ah[buf][rstage][k2] = (u32)hh[0] | ((u32)hh[1] << 16);
        *(u32*)&Am[buf][rstage][k2] = (u32)mm_[0] | ((u32)mm_[1] << 16);
        *(u32*)&Al[buf][rstage][k2] = (u32)ll[0] | ((u32)ll[1] << 16);
    };

    float2 xv0 = *(const float2*)&X[(size_t)rstage * 1024 + k2];
    stage(0, xv0);
    float2 xva = *(const float2*)&X[(size_t)rstage * 1024 + 32 + k2];
    float2 xvb = *(const float2*)&X[(size_t)rstage * 1024 + 64 + k2];

    for (int s = 0; s < 32; ++s) {
        __syncthreads();                   // tile s staged & visible
        int buf = s & 1;
        if (s < 31) {
            stage(buf ^ 1, xva);           // stage tile s+1
            xva = xvb;
            if (s < 30)
                xvb = *(const float2*)&X[(size_t)rstage * 1024 + (s + 3) * 32 + k2];
        }
        short8 ah = *(const short8*)&Ah[buf][l15][q4 * 8];
        short8 am = *(const short8*)&Am[buf][l15][q4 * 8];
        short8 al = *(const short8*)&Al[buf][l15][q4 * 8];
        size_t fo = ((size_t)(w * 32 + s) * 64 + lane) * 8;
        short8 bh_ = *(const short8*)&wfh[fo];
        short8 bm_ = *(const short8*)&wfm[fo];
        short8 bl_ = *(const short8*)&wfl[fo];
        acc = __builtin_amdgcn_mfma_f32_16x16x32_bf16(ah, bh_, acc, 0, 0, 0);
        acc = __builtin_amdgcn_mfma_f32_16x16x32_bf16(ah, bm_, acc, 0, 0, 0);
        acc = __builtin_amdgcn_mfma_f32_16x16x32_bf16(am, bh_, acc, 0, 0, 0);
        acc = __builtin_amdgcn_mfma_f32_16x16x32_bf16(ah, bl_, acc, 0, 0, 0);
        acc = __builtin_amdgcn_mfma_f32_16x16x32_bf16(am, bm_, acc, 0, 0, 0);
        acc = __builtin_amdgcn_mfma_f32_16x16x32_bf16(al, bh_, acc, 0, 0, 0);
    }

    // C frag: col = w*16 + (lane&15), row = q4*4 + i
#pragma unroll
    for (int i = 0; i < 4; ++i) {
        int row = n0 + q4 * 4 + i;
        size_t a = ((size_t)b * 1024 + row) * 64 + w * 16 + l15;
        h2f[a] = acc[i];
        h2hi[a] = f2bf(acc[i]);
    }
}

// ---------------------------------------------------------------- K2: L1 fused masked attention (round-19, control)
template <int DK, int NH, int ORS, int RT>
__global__ __launch_bounds__(256, 4) void attn6(const u16* __restrict__ hhi,
                                                const float* __restrict__ hf,
                                                const u32* __restrict__ adjx,
                                                const float* __restrict__ bias,
                                                float* __restrict__ outp) {
    constexpr int CR   = DK / 8;
    constexpr int NC   = DK / 32;
    constexpr int LGCR = (CR == 16) ? 4 : 3;
    constexpr int RPI  = 64 / CR;
    constexpr int NI   = 16 / RPI;
    constexpr int RW   = RT / 4;
    constexpr int RS   = RW / 16;
    constexpr int NBH  = NH * 16;
    constexpr int CMAX = 16;
    constexpr int HBUF = 64 * DK;         // u16 per staging buffer
    const u32 NEGK = 0xFF800000u;

    int bx = blockIdx.x;
    int bh = bx % NBH, tile = bx / NBH;   // XCD swizzle: bx%8 == bh%8
    int hd = (NH == 1) ? 0 : (bh & (NH - 1));
    int b  = (NH == 1) ? bh : (bh >> 3);
    int n0 = tile * RT;
    const u16*   Hhi = hhi + (size_t)bh * 1024 * DK;
    const float* Hf  = hf  + (size_t)bh * 1024 * DK;
    const float* bs  = bias + (size_t)hd * DK;
    float* ob = outp + (size_t)b * 1024 * ORS + (size_t)hd * DK;

    __shared__ __attribute__((aligned(16))) char smem[2 * HBUF * 2];   // 32768 B
    u16* Ksh = (u16*)smem;
    int   (*candm)[CMAX] = (int(*)[CMAX])smem;               // 8 KB @ 0
    float (*cands)[CMAX] = (float(*)[CMAX])(smem + 8192);    // 8 KB @ 8K
    int*   cnt           = (int*)(smem + 16384);             // 512 B @ 16K
    int*   wl            = (int*)(smem + 16896);             // 8 KB @ 16.5K
    int*   wln           = (int*)(smem + 25088);             // 4 B

    int t = threadIdx.x, lane = t & 63, w = t >> 6;
    int l15 = lane & 15, q4 = lane >> 4;

    uint2 adm[RS][4];
#pragma unroll
    for (int rs = 0; rs < RS; ++rs)
#pragma unroll
        for (int rg = 0; rg < 4; ++rg) {
            int row = w * RW + rs * 16 + q4 * 4 + rg;
            adm[rs][rg] = *(const uint2*)&adjx[((size_t)(n0 + row) * 16 + l15) * 2];
        }

    short8 af[RS][NC];
#pragma unroll
    for (int rs = 0; rs < RS; ++rs) {
        int ar = n0 + w * RW + rs * 16 + l15;
#pragma unroll
        for (int c = 0; c < NC; ++c)
            af[rs][c] = *(const short8*)&Hhi[(size_t)ar * DK + c * 32 + q4 * 8];
    }

    int mb = w * 16 + (lane >> LGCR);
    int sl = lane & (CR - 1);
    u32 goff[NI];
#pragma unroll
    for (int i = 0; i < NI; ++i) {
        int m = mb + i * RPI;
        goff[i] = (u32)(m * DK + ((sl ^ (m & (CR - 1))) << 3));
    }

    float t0[RS][4], t1[RS][4];
#pragma unroll
    for (int rs = 0; rs < RS; ++rs)
#pragma unroll
        for (int rg = 0; rg < 4; ++rg) {
            t0[rs][rg] = __uint_as_float(NEGK);
            t1[rs][rg] = __uint_as_float(NEGK);
        }

    {
        const u16* gp = Hhi;
#pragma unroll
        for (int i = 0; i < NI; ++i)
            __builtin_amdgcn_global_load_lds(
                (const GLOBAL_AS u32*)(gp + goff[i]),
                (LDS_AS u32*)&Ksh[w * 16 * DK + i * 512], 16, 0, 0);
    }
    for (int m0 = 0; m0 < 1024; m0 += 64) {
        int buf = (m0 >> 6) & 1;
        if (m0 + 64 < 1024) {
            const u16* gp = Hhi + (size_t)(m0 + 64) * DK;
#pragma unroll
            for (int i = 0; i < NI; ++i)
                __builtin_amdgcn_global_load_lds(
                    (const GLOBAL_AS u32*)(gp + goff[i]),
                    (LDS_AS u32*)&Ksh[(buf ^ 1) * HBUF + w * 16 * DK + i * 512], 16, 0, 0);
            asm volatile("s_waitcnt vmcnt(4)" ::: "memory");
        } else {
            asm volatile("s_waitcnt vmcnt(0)" ::: "memory");
        }
        __builtin_amdgcn_sched_barrier(0);
        asm volatile("s_barrier" ::: "memory");       // RAW: everyone's tile t landed

        const u16* Kb = Ksh + buf * HBUF;
        int J0 = m0 >> 4, shb = J0 & 31;
        u32 wmsel[RS][4];
#pragma unroll
        for (int rs = 0; rs < RS; ++rs)
#pragma unroll
            for (int rg = 0; rg < 4; ++rg)
                wmsel[rs][rg] = (J0 & 32) ? adm[rs][rg].y : adm[rs][rg].x;
#pragma unroll
        for (int mt = 0; mt < 4; ++mt) {
            int mrow = mt * 16 + l15;
            short8 bf[NC];
#pragma unroll
            for (int c = 0; c < NC; ++c) {
                int slot = (c * 4 + q4) ^ (mrow & (CR - 1));
                bf[c] = *(const short8*)&Kb[mrow * DK + slot * 8];
            }
            int jcol = m0 + mt * 16 + l15;
#pragma unroll
            for (int rs = 0; rs < RS; ++rs) {
                f32x4 acc = {0.f, 0.f, 0.f, 0.f};
#pragma unroll
                for (int c = 0; c < NC; ++c)
                    acc = __builtin_amdgcn_mfma_f32_16x16x32_bf16(af[rs][c], bf[c], acc, 0, 0, 0);
#pragma unroll
                for (int rg = 0; rg < 4; ++rg) {
                    u32 pk = (__float_as_uint(acc[rg]) & 0xFFFFFC00u) | (u32)jcol; // v_and_or
                    u32 msk = (u32)__builtin_amdgcn_sbfe((int)wmsel[rs][rg], shb + mt, 1);
                    u32 pmu = (pk & msk) | (NEGK & ~msk);                          // v_bfi
                    float tf = __uint_as_float(pmu);
                    t1[rs][rg] = __builtin_amdgcn_fmed3f(tf, t0[rs][rg], t1[rs][rg]);
                    t0[rs][rg] = fmaxf(t0[rs][rg], tf);
                }
            }
        }
        asm volatile("s_barrier" ::: "memory");       // WAR: all waves done with buf
    }
    __syncthreads();                       // all staging dead; aliases usable
    for (int u = t; u < RT; u += 256) cnt[u] = 0;
    if (t == 0) *wln = 0;
    __syncthreads();

#pragma unroll
    for (int rs = 0; rs < RS; ++rs)
#pragma unroll
        for (int rg = 0; rg < 4; ++rg) {
            float m = t0[rs][rg];
#pragma unroll
            for (int off = 1; off < 16; off <<= 1) m = fmaxf(m, __shfl_xor(m, off));
            float thr = m - (100.0f + 0.04f * fabsf(m));
            int row = w * RW + rs * 16 + q4 * 4 + rg;
            if (t0[rs][rg] > thr) {
                int p = atomicAdd(&cnt[row], 1);
                if (p < CMAX) candm[row][p] = (int)(__float_as_uint(t0[rs][rg]) & 1023u);
            }
            if (t1[rs][rg] > thr) {
                int p = atomicAdd(&cnt[row], 1);
                if (p < CMAX) candm[row][p] = (int)(__float_as_uint(t1[rs][rg]) & 1023u);
            }
        }
    __syncthreads();

    // compact (row,ci) worklist
    if (t < RT) {
        int kc = cnt[t]; if (kc > CMAX) kc = CMAX;
        int base = atomicAdd(wln, kc);
        for (int i = 0; i < kc; ++i) wl[base + i] = (t << 4) | i;
    }
    __syncthreads();

    // exact fp32 dots: one 8-lane group per candidate, coalesced 128B segments
    {
        int M = *wln;
        int g = t >> 3, l = t & 7;
        for (int e = g; e < M; e += 32) {
            int pk = wl[e];
            int row = pk >> 4, ci = pk & 15;
            const float* qa = Hf + (size_t)(n0 + row) * DK + l * (DK / 8);
            const float* kb = Hf + (size_t)candm[row][ci] * DK + l * (DK / 8);
            float acc = 0.f;
#pragma unroll
            for (int d = 0; d < DK / 8; d += 4) {
                float4 a  = *(const float4*)&qa[d];
                float4 bv = *(const float4*)&kb[d];
                acc += a.x * bv.x + a.y * bv.y + a.z * bv.z + a.w * bv.w;
            }
            acc += __shfl_xor(acc, 4);
            acc += __shfl_xor(acc, 2);
            acc += __shfl_xor(acc, 1);
            if (l == 0) cands[row][ci] = acc;
        }
    }
    __syncthreads();

    for (int row = t; row < RT; row += 256) {
        int kc = cnt[row]; if (kc > CMAX) kc = CMAX;
        float M = -3e38f;
        for (int i = 0; i < kc; ++i) M = fmaxf(M, cands[row][i]);
        float L = 0.f;
        for (int i = 0; i < kc; ++i) { float p = expf(cands[row][i] - M); cands[row][i] = p; L += p; }
        float inv = 1.f / L;
        for (int i = 0; i < kc; ++i) cands[row][i] *= inv;
    }
    __syncthreads();

    constexpr int D4 = DK / 4;
    for (int e = t; e < RT * D4; e += 256) {
        int row = e / D4, d4 = (e % D4) * 4;
        int kc = cnt[row]; if (kc > CMAX) kc = CMAX;
        float4 o = *(const float4*)&bs[d4];
        for (int i = 0; i < kc; ++i) {
            float p = cands[row][i];
            const float4 hv = *(const float4*)&Hf[(size_t)candm[row][i] * DK + d4];
            o.x += p * hv.x; o.y += p * hv.y; o.z += p * hv.z; o.w += p * hv.w;
        }
        o.x = o.x > 0.f ? o.x : 0.01f * o.x;
        o.y = o.y > 0.f ? o.y : 0.01f * o.y;
        o.z = o.z > 0.f ? o.z : 0.01f * o.z;
        o.w = o.w > 0.f ? o.w : 0.01f * o.w;
        *(float4*)&ob[(size_t)(n0 + row) * ORS + d4] = o;
    }
}

// ---------------------------------------------------------------- K4: L2 fused masked attention
__global__ __launch_bounds__(256) void attn6w(const u16* __restrict__ hhi,
                                              const float* __restrict__ hf,
                                              const u32* __restrict__ adjx,
                                              const float* __restrict__ bias,
                                              float* __restrict__ outp) {
    constexpr int DK = 64, NC = 2, CMAX = 16;
    constexpr int QR = 128;
    constexpr int HBUF = QR * DK;
    const u32 NEGK = 0xFF800000u;

    int bx = blockIdx.x;
    int b = bx & 15, tile = bx >> 4;
    int n0 = tile * 64;
    const u16*   Hhi = hhi + (size_t)b * 1024 * DK;
    const float* Hf  = hf  + (size_t)b * 1024 * DK;
    float* ob = outp + (size_t)b * 1024 * 64;

    __shared__ __attribute__((aligned(16))) u16 Ksh[2 * HBUF];
    int   (*candm)[CMAX] = (int(*)[CMAX])Ksh;                // 4 KB @ 0
    float (*cands)[CMAX] = (float(*)[CMAX])(Ksh + 2048);     // 4 KB @ 4K
    int* cnt = (int*)(Ksh + 4096);                           // 256 B @ 8K
    int* wl  = (int*)(Ksh + 4224);                           // 4 KB @ 8.25K
    int* wln = (int*)(Ksh + 6272);                           // 4 B @ 12.25K

    int t = threadIdx.x, lane = t & 63, w = t >> 6;
    int l15 = lane & 15, q4 = lane >> 4;

    uint2 adm[4];
#pragma unroll
    for (int rg = 0; rg < 4; ++rg) {
        int row = w * 16 + q4 * 4 + rg;
        adm[rg] = *(const uint2*)&adjx[((size_t)(n0 + row) * 16 + l15) * 2];
    }

    short8 af[NC];
    {
        int ar = n0 + w * 16 + l15;
#pragma unroll
        for (int c = 0; c < NC; ++c)
            af[c] = *(const short8*)&Hhi[(size_t)ar * DK + c * 32 + q4 * 8];
    }

    u32 goff[4];
#pragma unroll
    for (int i = 0; i < 4; ++i) {
        int q = i * 64 + lane;
        int lr = w * 32 + (q >> 3);
        int sl = q & 7;
        goff[i] = (u32)(lr * DK + ((sl ^ (lr & 7)) << 3));
    }

    float t0[4], t1[4];
#pragma unroll
    for (int rg = 0; rg < 4; ++rg) { t0[rg] = __uint_as_float(NEGK); t1[rg] = __uint_as_float(NEGK); }

#pragma unroll
    for (int i = 0; i < 4; ++i)
        __builtin_amdgcn_global_load_lds(
            (const GLOBAL_AS u32*)(Hhi + goff[i]),
            (LDS_AS u32*)&Ksh[w * 32 * DK + i * 512], 16, 0, 0);

    for (int s = 0; s < 8; ++s) {
        __syncthreads();
        if (s < 7) {
            const u16* gp = Hhi + (size_t)(s + 1) * QR * DK;
            int obuf = (s + 1) & 1;
#pragma unroll
            for (int i = 0; i < 4; ++i)
                __builtin_amdgcn_global_load_lds(
                    (const GLOBAL_AS u32*)(gp + goff[i]),
                    (LDS_AS u32*)&Ksh[obuf * HBUF + w * 32 * DK + i * 512], 16, 0, 0);
        }
        const u16* Kb = Ksh + (s & 1) * HBUF;
#pragma unroll
        for (int mq = 0; mq < 2; ++mq) {
            int m0 = s * QR + mq * 64;
            int J0 = m0 >> 4, shb = J0 & 31;
            u32 wmsel[4];
#pragma unroll
            for (int rg = 0; rg < 4; ++rg) wmsel[rg] = (J0 & 32) ? adm[rg].y : adm[rg].x;
#pragma unroll
            for (int mt = 0; mt < 4; ++mt) {
                int mloc = mq * 64 + mt * 16 + l15;
                short8 bf[NC];
#pragma unroll
                for (int c = 0; c < NC; ++c) {
                    int slot = (c * 4 + q4) ^ (mloc & 7);
                    bf[c] = *(const short8*)&Kb[mloc * DK + slot * 8];
                }
                int jcol = m0 + mt * 16 + l15;
                f32x4 acc = {0.f, 0.f, 0.f, 0.f};
#pragma unroll
                for (int c = 0; c < NC; ++c)
                    acc = __builtin_amdgcn_mfma_f32_16x16x32_bf16(af[c], bf[c], acc, 0, 0, 0);
#pragma unroll
                for (int rg = 0; rg < 4; ++rg) {
                    u32 pk = (__float_as_uint(acc[rg]) & 0xFFFFFC00u) | (u32)jcol;
                    u32 msk = (u32)__builtin_amdgcn_sbfe((int)wmsel[rg], shb + mt, 1);
                    u32 pmu = (pk & msk) | (NEGK & ~msk);
                    float tf = __uint_as_float(pmu);
                    t1[rg] = __builtin_amdgcn_fmed3f(tf, t0[rg], t1[rg]);
                    t0[rg] = fmaxf(t0[rg], tf);
                }
            }
        }
    }
    __syncthreads();
    if (t < 64) cnt[t] = 0;
    if (t == 0) *wln = 0;
    __syncthreads();

#pragma unroll
    for (int rg = 0; rg < 4; ++rg) {
        float m = t0[rg];
#pragma unroll
        for (int off = 1; off < 16; off <<= 1) m = fmaxf(m, __shfl_xor(m, off));
        float thr = m - (100.0f + 0.04f * fabsf(m));
        int row = w * 16 + q4 * 4 + rg;
        if (t0[rg] > thr) {
            int p = atomicAdd(&cnt[row], 1);
            if (p < CMAX) candm[row][p] = (int)(__float_as_uint(t0[rg]) & 1023u);
        }
        if (t1[rg] > thr) {
            int p = atomicAdd(&cnt[row], 1);
            if (p < CMAX) candm[row][p] = (int)(__float_as_uint(t1[rg]) & 1023u);
        }
    }
    __syncthreads();

    // compact (row,ci) worklist
    if (t < 64) {
        int kc = cnt[t]; if (kc > CMAX) kc = CMAX;
        int base = atomicAdd(wln, kc);
        for (int i = 0; i < kc; ++i) wl[base + i] = (t << 4) | i;
    }
    __syncthreads();

    // exact fp32 dots: one 8-lane group per candidate
    {
        int M = *wln;
        int g = t >> 3, l = t & 7;
        for (int e = g; e < M; e += 32) {
            int pk = wl[e];
            int row = pk >> 4, ci = pk & 15;
            const float* qa = Hf + (size_t)(n0 + row) * DK + l * (DK / 8);
            const float* kb = Hf + (size_t)candm[row][ci] * DK + l * (DK / 8);
            float acc = 0.f;
#pragma unroll
            for (int d = 0; d < DK / 8; d += 4) {
                float4 a  = *(const float4*)&qa[d];
                float4 bv = *(const float4*)&kb[d];
                acc += a.x * bv.x + a.y * bv.y + a.z * bv.z + a.w * bv.w;
            }
            acc += __shfl_xor(acc, 4);
            acc += __shfl_xor(acc, 2);
            acc += __shfl_xor(acc, 1);
            if (l == 0) cands[row][ci] = acc;
        }
    }
    __syncthreads();

    if (t < 64) {
        int row = t;
        int kc = cnt[row]; if (kc > CMAX) kc = CMAX;
        float M = -3e38f;
        for (int i = 0; i < kc; ++i) M = fmaxf(M, cands[row][i]);
        float L = 0.f;
        for (int i = 0; i < kc; ++i) { float p = expf(cands[row][i] - M); cands[row][i] = p; L += p; }
        float inv = 1.f / L;
        for (int i = 0; i < kc; ++i) cands[row][i] *= inv;
    }
    __syncthreads();

    for (int e = t; e < 64 * 16; e += 256) {
        int row = e / 16, d4 = (e % 16) * 4;
        int kc = cnt[row]; if (kc > CMAX) kc = CMAX;
        float4 o = *(const float4*)&bias[d4];
        for (int i = 0; i < kc; ++i) {
            float p = cands[row][i];
            const float4 hv = *(const float4*)&Hf[(size_t)candm[row][i] * DK + d4];
            o.x += p * hv.x; o.y += p * hv.y; o.z += p * hv.z; o.w += p * hv.w;
        }
        o.x = o.x > 0.f ? o.x : 0.01f * o.x;
        o.y = o.y > 0.f ? o.y : 0.01f * o.y;
        o.z = o.z > 0.f ? o.z : 0.01f * o.z;
        o.w = o.w > 0.f ? o.w : 0.01f * o.w;
        *(float4*)&ob[(size_t)(n0 + row) * 64 + d4] = o;
    }
}

// ---------------------------------------------------------------- launcher
extern "C" void kernel_launch(void* const* d_in, const int* in_sizes, int n_in,
                              void* d_out, int out_size, void* d_ws, size_t ws_size,
                              hipStream_t stream) {
    (void)in_sizes; (void)n_in; (void)out_size; (void)ws_size;
    const float* flow_x = (const float*)d_in[0];   // [16,1024,64]
    const float* graph  = (const float*)d_in[1];   // [1024,1024]
    const float* Wh     = (const float*)d_in[2];   // [8,64,128]
    const float* bh     = (const float*)d_in[3];   // [8,128]
    const float* W_out  = (const float*)d_in[4];   // [1024,64]
    const float* b_out  = (const float*)d_in[5];   // [64]
    float* out = (float*)d_out;                    // [16,1024,64] fp32

    // workspace carve-up (~168 MB; all 16B-aligned)
    float* h_f32 = (float*)d_ws;                       // 16,777,216 f  [bh][n][128]
    float* x2    = h_f32 + 16777216;                   // 16,777,216 f  [b][n][1024]
    float* h2    = x2 + 16777216;                      //  1,048,576 f  [b][n][64]
    u16*  h_hi   = (u16*)(h2 + 1048576);               // 16,777,216 u16
    u16*  h2_hi  = h_hi + 16777216;                    //  1,048,576 u16
    u32*  adjx   = (u32*)(h2_hi + 1048576);            //     32,768 u32 (residue-bucketed)
    u16*  wfh    = (u16*)(adjx + 32768);               //     65,536 u16 (W_out hi frags)
    u16*  wfm    = wfh + 65536;                        //     65,536 u16 (W_out mid frags)
    u16*  wfl    = wfm + 65536;                        //     65,536 u16 (W_out lo frags)
    u16*  whf    = wfl + 65536;                        //     65,536 u16 (Wh hi frags)
    u16*  whm    = whf + 65536;                        //     65,536 u16 (Wh mid frags)
    u16*  whl    = whm + 65536;                        //     65,536 u16 (Wh lo frags)

    prep<<<1088, 256, 0, stream>>>(graph, W_out, Wh, adjx, wfh, wfm, wfl, whf, whm, whl);
    proj1m<<<dim3(128, 16), 256, 0, stream>>>(flow_x, whf, whm, whl, h_f32, h_hi);
    attn6<128, 8, 1024, 128><<<1024, 256, 0, stream>>>(h_hi, h_f32, adjx, bh, x2);
    proj2m<<<1024, 256, 0, stream>>>(x2, wfh, wfm, wfl, h2, h2_hi);
    attn6w<<<256, 256, 0, stream>>>(h2_hi, h2, adjx, b_out, out);
}